// Round 7
// baseline (444.064 us; speedup 1.0000x reference)
//
#include <hip/hip_runtime.h>
#include <math.h>

#define D 128
#define NB 8
#define NN1 128
#define NN2 512
#define ROWS1 (NB * NN1)          // 1024
#define ROWS2 (NB * NN2)          // 4096
#define ROWS (ROWS1 + ROWS2)      // 5120
#define CAP1 96
#define CAP2 160
#define CSR_ELEMS ((size_t)ROWS1 * CAP1 + (size_t)ROWS2 * CAP2)

__device__ __forceinline__ void resolve_row(int row, int& base_row, size_t& cbase,
                                            int& N) {
    if (row < ROWS1) {
        base_row = row & ~127;
        cbase = (size_t)row * CAP1;
        N = NN1;
    } else {
        int r = row - ROWS1;
        base_row = ROWS1 + (r & ~511);
        cbase = (size_t)ROWS1 * CAP1 + (size_t)r * CAP2;
        N = NN2;
    }
}

// ---------------- CSR build (4 waves = 4 rows / block) + out zero ----------
__global__ __launch_bounds__(256) void k_csr(const float* __restrict__ adj1,
                                             const float* __restrict__ adj2,
                                             unsigned short* __restrict__ csr,
                                             int* __restrict__ nnz,
                                             float* __restrict__ out) {
    int t = threadIdx.x;
    if (blockIdx.x == 0 && t < NB * 5) out[t] = 0.f;
    int row = blockIdx.x * 4 + (t >> 6);
    int lane = t & 63;
    int base_row, N;
    size_t cbase;
    resolve_row(row, base_row, cbase, N);
    int cap = (row < ROWS1) ? CAP1 : CAP2;
    const float* arow = (row < ROWS1) ? adj1 + (size_t)row * NN1
                                      : adj2 + (size_t)(row - ROWS1) * NN2;
    int cnt = 0;
    for (int c0 = 0; c0 < N; c0 += 64) {
        float v = arow[c0 + lane];
        unsigned long long m = __ballot(v > 0.f);
        int rank = __popcll(m & ((1ull << lane) - 1ull));
        if (v > 0.f && cnt + rank < cap)
            csr[cbase + cnt + rank] = (unsigned short)(c0 + lane);
        cnt += __popcll(m);
    }
    if (lane == 0) nnz[row] = cnt < cap ? cnt : cap;
}

// ---- shared GEMM building block: 16 rows in xs, thread = (d0, rg) owns
// rows rg*4..rg*4+3 at columns d0 and d0+64. Entirely wave-local on LDS. ----
#define GEMM16(XS, W, B0, B1, OUTSTMT)                                        \
    {                                                                         \
        float acc[4][2];                                                      \
        _Pragma("unroll") for (int u = 0; u < 4; ++u) {                       \
            acc[u][0] = (B0); acc[u][1] = (B1);                               \
        }                                                                     \
        for (int k0 = 0; k0 < D; k0 += 4) {                                   \
            float w00 = (W)[(k0 + 0) * D + d0], w01 = (W)[(k0 + 0) * D + d0 + 64]; \
            float w10 = (W)[(k0 + 1) * D + d0], w11 = (W)[(k0 + 1) * D + d0 + 64]; \
            float w20 = (W)[(k0 + 2) * D + d0], w21 = (W)[(k0 + 2) * D + d0 + 64]; \
            float w30 = (W)[(k0 + 3) * D + d0], w31 = (W)[(k0 + 3) * D + d0 + 64]; \
            _Pragma("unroll") for (int u = 0; u < 4; ++u) {                   \
                float4 xv = *(const float4*)&XS[rg * 4 + u][k0];              \
                acc[u][0] += xv.x * w00 + xv.y * w10 + xv.z * w20 + xv.w * w30; \
                acc[u][1] += xv.x * w01 + xv.y * w11 + xv.z * w21 + xv.w * w31; \
            }                                                                 \
        }                                                                     \
        _Pragma("unroll") for (int u = 0; u < 4; ++u) {                       \
            _Pragma("unroll") for (int hf = 0; hf < 2; ++hf) {                \
                int rr = rg * 4 + u;                                          \
                int dd = d0 + hf * 64;                                        \
                float av = acc[u][hf];                                        \
                OUTSTMT;                                                      \
            }                                                                 \
        }                                                                     \
    }

// ----- k_h0: embed (g = h_in @ nodeW) + h = g@W+b + hA = h@A, 16 rows -----
__global__ __launch_bounds__(256) void k_h0(
    const float* __restrict__ h1in, const float* __restrict__ h2in,
    const float* __restrict__ nodeW, const float* __restrict__ W,
    const float* __restrict__ bias, const float* __restrict__ A,
    float* __restrict__ g, float* __restrict__ hOut, float* __restrict__ hAOut) {
    int row0 = blockIdx.x * 16;
    int t = threadIdx.x;
    int d0 = t & 63, rg = t >> 6;
    __shared__ float hin[16][56];
    __shared__ float xs[16][D];
    __shared__ float hs[16][D];
    {   // wave-local staging of 4 input rows
        int lane = t & 63;
        const float* src = (row0 < ROWS1) ? h1in + (size_t)row0 * 54
                                          : h2in + (size_t)(row0 - ROWS1) * 54;
        for (int idx = lane; idx < 4 * 54; idx += 64) {
            int r = idx / 54, c = idx - r * 54;
            hin[rg * 4 + r][c] = src[(size_t)(rg * 4 + r) * 54 + c];
        }
    }
    // embed: 4 rows x 2 cols per thread (wave-local hin rows)
    {
        float acc[4][2] = {{0.f,0.f},{0.f,0.f},{0.f,0.f},{0.f,0.f}};
        for (int k = 0; k < 54; ++k) {
            float w0 = nodeW[k * D + d0], w1 = nodeW[k * D + d0 + 64];
#pragma unroll
            for (int u = 0; u < 4; ++u) {
                float x = hin[rg * 4 + u][k];
                acc[u][0] += x * w0;
                acc[u][1] += x * w1;
            }
        }
#pragma unroll
        for (int u = 0; u < 4; ++u)
#pragma unroll
            for (int hf = 0; hf < 2; ++hf) {
                int rr = rg * 4 + u, dd = d0 + hf * 64;
                xs[rr][dd] = acc[u][hf];
                g[((size_t)row0 + rr) * D + dd] = acc[u][hf];
            }
    }
    float b0 = bias[d0], b1 = bias[d0 + 64];
    GEMM16(xs, W, b0, b1,
           { hs[rr][dd] = av; hOut[((size_t)row0 + rr) * D + dd] = av; })
    GEMM16(hs, A, 0.f, 0.f,
           { hAOut[((size_t)row0 + rr) * D + dd] = av; })
}

// ---- sparse S row + softmax stats (unchanged from R6) ----
__global__ __launch_bounds__(128) void k_Ssp(const float* __restrict__ h,
                                             const float* __restrict__ hA,
                                             const unsigned short* __restrict__ csr,
                                             const int* __restrict__ nnz,
                                             float* __restrict__ svals,
                                             float2* __restrict__ rowstat) {
    int row = blockIdx.x;
    int t = threadIdx.x;
    int base_row, N;
    size_t cbase;
    resolve_row(row, base_row, cbase, N);
    int n = nnz[row];
    int grp = t >> 4, u = t & 15;
    const float* hrow = h + (size_t)row * D + u * 8;
    const float* hArow = hA + (size_t)row * D + u * 8;
    float4 hi0 = *(const float4*)&hrow[0], hi1 = *(const float4*)&hrow[4];
    float4 ai0 = *(const float4*)&hArow[0], ai1 = *(const float4*)&hArow[4];
    __shared__ float sv[CAP2];
    for (int s0 = 0; s0 < n; s0 += 16) {
        int sa = s0 + grp;
        int sb = sa + 8;
        float pa = 0.f, pb = 0.f;
        if (sa < n) {
            int jrow = base_row + csr[cbase + sa];
            const float* hj = h + (size_t)jrow * D + u * 8;
            const float* aj = hA + (size_t)jrow * D + u * 8;
            float4 hj0 = *(const float4*)&hj[0], hj1 = *(const float4*)&hj[4];
            float4 aj0 = *(const float4*)&aj[0], aj1 = *(const float4*)&aj[4];
            pa = hi0.x * aj0.x + hi0.y * aj0.y + hi0.z * aj0.z + hi0.w * aj0.w +
                 hi1.x * aj1.x + hi1.y * aj1.y + hi1.z * aj1.z + hi1.w * aj1.w +
                 ai0.x * hj0.x + ai0.y * hj0.y + ai0.z * hj0.z + ai0.w * hj0.w +
                 ai1.x * hj1.x + ai1.y * hj1.y + ai1.z * hj1.z + ai1.w * hj1.w;
        }
        if (sb < n) {
            int jrow = base_row + csr[cbase + sb];
            const float* hj = h + (size_t)jrow * D + u * 8;
            const float* aj = hA + (size_t)jrow * D + u * 8;
            float4 hj0 = *(const float4*)&hj[0], hj1 = *(const float4*)&hj[4];
            float4 aj0 = *(const float4*)&aj[0], aj1 = *(const float4*)&aj[4];
            pb = hi0.x * aj0.x + hi0.y * aj0.y + hi0.z * aj0.z + hi0.w * aj0.w +
                 hi1.x * aj1.x + hi1.y * aj1.y + hi1.z * aj1.z + hi1.w * aj1.w +
                 ai0.x * hj0.x + ai0.y * hj0.y + ai0.z * hj0.z + ai0.w * hj0.w +
                 ai1.x * hj1.x + ai1.y * hj1.y + ai1.z * hj1.z + ai1.w * hj1.w;
        }
#pragma unroll
        for (int o = 8; o > 0; o >>= 1) {
            pa += __shfl_xor(pa, o);
            pb += __shfl_xor(pb, o);
        }
        if (u == 0) {
            if (sa < n) sv[sa] = pa;
            if (sb < n) sv[sb] = pb;
        }
    }
    __syncthreads();
    if (t < 64) {
        float m = -3.4e38f;
        for (int s = t; s < n; s += 64) m = fmaxf(m, sv[s]);
#pragma unroll
        for (int o = 32; o > 0; o >>= 1) m = fmaxf(m, __shfl_xor(m, o));
        float sum = 0.f;
        for (int s = t; s < n; s += 64) sum += expf(sv[s] - m);
#pragma unroll
        for (int o = 32; o > 0; o >>= 1) sum += __shfl_xor(sum, o);
        if (t == 0) rowstat[row] = make_float2(m, 1.f / sum);
    }
    for (int s = t; s < n; s += 128) svals[cbase + s] = sv[s];
}

// ---- hpgate phase: one wave handles 4 rows sequentially, writes xs rows ----
__device__ __forceinline__ void hpgate16(
    int row0, int t, const float* __restrict__ hIn, float* __restrict__ g,
    const float* __restrict__ svals, const float2* __restrict__ rowstat,
    const unsigned short* __restrict__ csr, const int* __restrict__ nnz,
    const float* __restrict__ gW, float gb0, float (*xs)[D],
    float av_s[4][CAP2], int ai_s[4][CAP2], int writeG) {
    int lane = t & 63, wv = t >> 6;
    for (int rr = 0; rr < 4; ++rr) {
        int xrow = wv * 4 + rr;
        int row = row0 + xrow;
        int base_row, N;
        size_t cbase;
        resolve_row(row, base_row, cbase, N);
        int n = nnz[row];
        for (int s = lane; s < n; s += 64) {
            int jrow = base_row + csr[cbase + s];
            float2 st = rowstat[jrow];
            av_s[wv][s] = expf(svals[cbase + s] - st.x) * st.y;
            ai_s[wv][s] = jrow;
        }
        // wave-local LDS: no barrier needed
        float a0[4] = {0.f, 0.f, 0.f, 0.f}, a1[4] = {0.f, 0.f, 0.f, 0.f};
        int s = 0;
        for (; s + 4 <= n; s += 4) {
#pragma unroll
            for (int q = 0; q < 4; ++q) {
                float av = av_s[wv][s + q];
                size_t jb = (size_t)ai_s[wv][s + q] * D;
                a0[q] += av * hIn[jb + lane];
                a1[q] += av * hIn[jb + lane + 64];
            }
        }
        for (; s < n; ++s) {
            float av = av_s[wv][s];
            size_t jb = (size_t)ai_s[wv][s] * D;
            a0[0] += av * hIn[jb + lane];
            a1[0] += av * hIn[jb + lane + 64];
        }
        float hv0 = fmaxf((a0[0] + a0[1]) + (a0[2] + a0[3]), 0.f);
        float hv1 = fmaxf((a1[0] + a1[1]) + (a1[2] + a1[3]), 0.f);
        float xv0 = g[(size_t)row * D + lane];
        float xv1 = g[(size_t)row * D + lane + 64];
        float part = xv0 * gW[lane] + xv1 * gW[lane + 64] +
                     hv0 * gW[D + lane] + hv1 * gW[D + lane + 64];
#pragma unroll
        for (int o = 32; o > 0; o >>= 1) part += __shfl_xor(part, o);
        float c = 1.f / (1.f + expf(-(part + gb0)));
        float g0 = c * xv0 + (1.f - c) * hv0;
        float g1 = c * xv1 + (1.f - c) * hv1;
        xs[xrow][lane] = g0;
        xs[xrow][lane + 64] = g1;
        if (writeG) {
            g[(size_t)row * D + lane] = g0;
            g[(size_t)row * D + lane + 64] = g1;
        }
    }
}

// ----- k_hgh: fused hpgate(layer l) + h/hA GEMMs (layer l+1), 16 rows -----
__global__ __launch_bounds__(256) void k_hgh(
    const float* __restrict__ hIn, float* __restrict__ g,
    const float* __restrict__ svals, const float2* __restrict__ rowstat,
    const unsigned short* __restrict__ csr, const int* __restrict__ nnz,
    const float* __restrict__ gW, const float* __restrict__ gb,
    const float* __restrict__ W, const float* __restrict__ bias,
    const float* __restrict__ A, float* __restrict__ hOut,
    float* __restrict__ hAOut) {
    int row0 = blockIdx.x * 16;
    int t = threadIdx.x;
    int d0 = t & 63, rg = t >> 6;
    __shared__ float xs[16][D];
    __shared__ float hs[16][D];
    __shared__ float av_s[4][CAP2];
    __shared__ int ai_s[4][CAP2];
    hpgate16(row0, t, hIn, g, svals, rowstat, csr, nnz, gW, gb[0], xs, av_s, ai_s, 1);
    float b0 = bias[d0], b1 = bias[d0 + 64];
    GEMM16(xs, W, b0, b1,
           { hs[rr][dd] = av; hOut[((size_t)row0 + rr) * D + dd] = av; })
    GEMM16(hs, A, 0.f, 0.f,
           { hAOut[((size_t)row0 + rr) * D + dd] = av; })
}

// ----- k_hgp: fused hpgate(layer 2) + pair-MLP precompute GEMMs -----------
__global__ __launch_bounds__(256) void k_hgp(
    const float* __restrict__ hIn, float* __restrict__ g,
    const float* __restrict__ svals, const float2* __restrict__ rowstat,
    const unsigned short* __restrict__ csr, const int* __restrict__ nnz,
    const float* __restrict__ gW, const float* __restrict__ gb,
    const float* __restrict__ WA, const float* __restrict__ WB,
    const float* __restrict__ bA, const float* __restrict__ bB,
    float* __restrict__ aA, float* __restrict__ aB) {
    int row0 = blockIdx.x * 16;
    int t = threadIdx.x;
    int d0 = t & 63, rg = t >> 6;
    __shared__ float xs[16][D];
    __shared__ float av_s[4][CAP2];
    __shared__ int ai_s[4][CAP2];
    hpgate16(row0, t, hIn, g, svals, rowstat, csr, nnz, gW, gb[0], xs, av_s, ai_s, 0);
    int g2 = (row0 >= ROWS1);
    const float* WAp = g2 ? WA + D * D : WA;
    const float* WBp = g2 ? WB + D * D : WB;
    float bA0 = g2 ? 0.f : bA[d0], bA1 = g2 ? 0.f : bA[d0 + 64];
    float bB0 = g2 ? 0.f : bB[d0], bB1 = g2 ? 0.f : bB[d0 + 64];
    GEMM16(xs, WAp, bA0, bA1, { aA[((size_t)row0 + rr) * D + dd] = av; })
    GEMM16(xs, WBp, bB0, bB1, { aB[((size_t)row0 + rr) * D + dd] = av; })
}

// --------- fused pair z-GEMM + energies + scaled atomic output ------------
__global__ __launch_bounds__(256) void k_pairz(
    const float* __restrict__ aA, const float* __restrict__ aB,
    const float* __restrict__ w2A, const float* __restrict__ w2B,
    const float* __restrict__ b2A, const float* __restrict__ b2B,
    const float* __restrict__ pos1, const float* __restrict__ pos2,
    const float* __restrict__ vr1, const float* __restrict__ vr2,
    const float* __restrict__ nm1, const float* __restrict__ nm2,
    const float* __restrict__ A_int, const float* __restrict__ rotor,
    const float* __restrict__ duff, const float* __restrict__ hbond,
    const float* __restrict__ hydro, const float* __restrict__ vdwc,
    const float* __restrict__ rotc, float* __restrict__ out) {
    int b = blockIdx.y;
    int itile = blockIdx.x >> 4, jtile = blockIdx.x & 15;
    int i0 = itile * 32, j0 = jtile * 32;
    int t = threadIdx.x;
    int tx = t & 15, ty = t >> 4;
    __shared__ float A1a[32][20], A1b[32][20], A2a[32][20], A2b[32][20];
    __shared__ float w2As[128], w2Bs[128];
    __shared__ float zAs[32][33], zBs[32][33];
    __shared__ float redc[8][4];
    if (t < 128) { w2As[t] = w2A[t]; w2Bs[t] = w2B[t]; }
    float zA[2][2] = {{0.f, 0.f}, {0.f, 0.f}};
    float zB[2][2] = {{0.f, 0.f}, {0.f, 0.f}};
    int half = t >> 7, idx = t & 127;
    int sr = idx >> 2, sc = (idx & 3) * 4;
    size_t grow = half ? (size_t)(ROWS1 + b * NN2 + j0 + sr)
                       : (size_t)(b * NN1 + i0 + sr);
    for (int hc = 0; hc < D; hc += 16) {
        __syncthreads();
        float4 va = *(const float4*)&aA[grow * D + hc + sc];
        float4 vb = *(const float4*)&aB[grow * D + hc + sc];
        if (half) { *(float4*)&A2a[sr][sc] = va; *(float4*)&A2b[sr][sc] = vb; }
        else      { *(float4*)&A1a[sr][sc] = va; *(float4*)&A1b[sr][sc] = vb; }
        __syncthreads();
#pragma unroll
        for (int hh = 0; hh < 16; hh += 4) {
            float4 wA = *(const float4*)&w2As[hc + hh];
            float4 wB = *(const float4*)&w2Bs[hc + hh];
            float4 xA0 = *(const float4*)&A1a[ty][hh];
            float4 xA1 = *(const float4*)&A1a[ty + 16][hh];
            float4 xB0 = *(const float4*)&A1b[ty][hh];
            float4 xB1 = *(const float4*)&A1b[ty + 16][hh];
            float4 yA0 = *(const float4*)&A2a[tx][hh];
            float4 yA1 = *(const float4*)&A2a[tx + 16][hh];
            float4 yB0 = *(const float4*)&A2b[tx][hh];
            float4 yB1 = *(const float4*)&A2b[tx + 16][hh];
#define RD4(xx, yy, ww) (fmaxf(xx.x + yy.x, 0.f) * ww.x + fmaxf(xx.y + yy.y, 0.f) * ww.y + \
                         fmaxf(xx.z + yy.z, 0.f) * ww.z + fmaxf(xx.w + yy.w, 0.f) * ww.w)
            zA[0][0] += RD4(xA0, yA0, wA); zA[0][1] += RD4(xA0, yA1, wA);
            zA[1][0] += RD4(xA1, yA0, wA); zA[1][1] += RD4(xA1, yA1, wA);
            zB[0][0] += RD4(xB0, yB0, wB); zB[0][1] += RD4(xB0, yB1, wB);
            zB[1][0] += RD4(xB1, yB0, wB); zB[1][1] += RD4(xB1, yB1, wB);
#undef RD4
        }
    }
#pragma unroll
    for (int u = 0; u < 2; ++u)
#pragma unroll
        for (int v = 0; v < 2; ++v) {
            zAs[ty + 16 * u][tx + 16 * v] = zA[u][v];
            zBs[ty + 16 * u][tx + 16 * v] = zB[u][v];
        }
    __syncthreads();
    int j2 = t & 31, ig = t >> 5;
    int jg = j0 + j2;
    size_t j_off = (size_t)b * NN2 + jg;
    float p2x = pos2[j_off * 3 + 0], p2y = pos2[j_off * 3 + 1], p2z = pos2[j_off * 3 + 2];
    float r2 = vr2[j_off], m2 = nm2[j_off];
    float zb2A = b2A[0], zb2B = b2B[0];
    float eV[4], e1[4], e2[4], eH[4];
#pragma unroll
    for (int ii = 0; ii < 4; ++ii) {
        int il = ig * 4 + ii;
        int iglob = i0 + il;
        size_t i_off = (size_t)b * NN1 + iglob;
        float zAv = zAs[il][j2] + zb2A;
        float zBv = zBs[il][j2] + zb2B;
        float dx = pos1[i_off * 3 + 0] - p2x;
        float dy = pos1[i_off * 3 + 1] - p2y;
        float dz = pos1[i_off * 3 + 2] - p2z;
        float dm = sqrtf(dx * dx + dy * dy + dz * dz + 1e-10f);
        if (dm < 0.5f) dm = 1e10f;
        float A_w = 1.f / (1.f + expf(-zAv));
        float B_w = tanhf(zBv) * 0.2f;
        float dm0 = vr1[i_off] + r2 + B_w;
        float dm0s = (dm0 < 1e-4f) ? 1.f : dm0;
        float rr = dm0s / dm;
        float rr2 = rr * rr;
        float rN = rr2 * rr2 * rr2;
        float evdw = fminf(rN * rN - 2.f * rN, 100.f);
        float mask = nm1[i_off] * m2;
        float Aamp = A_w * (0.0356f - 0.0178f) + 0.0178f;
        eV[ii] = Aamp * evdw * mask;
        float dmd = dm - dm0;
        size_t abase = (((size_t)b * 8) * NN1 + iglob) * NN2 + jg;
        float Ai1 = A_int[abase + (size_t)1 * NN1 * NN2];
        float Ai6 = A_int[abase + (size_t)6 * NN1 * NN2];
        float Ai7 = A_int[abase + (size_t)7 * NN1 * NN2];
        e1[ii] = fminf(fmaxf(dmd * Ai1 * (-1.f / 0.7f), 0.f), 1.f);
        e2[ii] = fminf(fmaxf(dmd * Ai7 * (-1.f / 0.7f), 0.f), 1.f);
        eH[ii] = fminf(fmaxf((1.5f - dmd) * Ai6, 0.f), 1.f);
    }
    float sV = (eV[0] + eV[1]) + (eV[2] + eV[3]);
    float s1 = (e1[0] + e1[1]) + (e1[2] + e1[3]);
    float s2 = (e2[0] + e2[1]) + (e2[2] + e2[3]);
    float sH = (eH[0] + eH[1]) + (eH[2] + eH[3]);
#pragma unroll
    for (int o = 16; o > 0; o >>= 1) {
        sV += __shfl_xor(sV, o);
        s1 += __shfl_xor(s1, o);
        s2 += __shfl_xor(s2, o);
        sH += __shfl_xor(sH, o);
    }
    if (j2 == 0) {
        redc[ig][0] = sV; redc[ig][1] = s1; redc[ig][2] = s2; redc[ig][3] = sH;
    }
    __syncthreads();
    if (t < 4) {
        float v = 0.f;
#pragma unroll
        for (int gg = 0; gg < 8; ++gg) v += redc[gg][t];
        float scl = 1.f / (1.f + rotc[0] * rotc[0] * rotor[b]);
        float coef;
        if (t == 0) coef = scl;
        else if (t == 3) coef = -hydro[0] * hydro[0] * scl;
        else coef = -hbond[0] * hbond[0] * scl;
        atomicAdd(&out[b * 5 + t], v * coef);
    }
    if (t == 4 && itile == 0 && jtile == 0) {
        float scl = 1.f / (1.f + rotc[0] * rotc[0] * rotor[b]);
        atomicAdd(&out[b * 5 + 4], duff[b] * vdwc[0] * vdwc[0] * scl);
    }
}

extern "C" void kernel_launch(void* const* d_in, const int* in_sizes, int n_in,
                              void* d_out, int out_size, void* d_ws, size_t ws_size,
                              hipStream_t stream) {
    const float* h1    = (const float*)d_in[0];
    const float* adj1  = (const float*)d_in[1];
    const float* h2    = (const float*)d_in[2];
    const float* adj2  = (const float*)d_in[3];
    const float* A_int = (const float*)d_in[4];
    const float* pos1  = (const float*)d_in[5];
    const float* pos2  = (const float*)d_in[6];
    const float* rotor = (const float*)d_in[7];
    const float* vr1   = (const float*)d_in[8];
    const float* vr2   = (const float*)d_in[9];
    const float* duff  = (const float*)d_in[10];
    const float* nm1   = (const float*)d_in[11];
    const float* nm2   = (const float*)d_in[12];
    const float* nodeW = (const float*)d_in[13];
    const float* gatW  = (const float*)d_in[14];
    const float* gatb  = (const float*)d_in[15];
    const float* gatA  = (const float*)d_in[16];
    const float* gateW = (const float*)d_in[17];
    const float* gateb = (const float*)d_in[18];
    const float* vA_W1 = (const float*)d_in[19];
    const float* vA_b1 = (const float*)d_in[20];
    const float* vA_W2 = (const float*)d_in[21];
    const float* vA_b2 = (const float*)d_in[22];
    const float* vB_W1 = (const float*)d_in[23];
    const float* vB_b1 = (const float*)d_in[24];
    const float* vB_W2 = (const float*)d_in[25];
    const float* vB_b2 = (const float*)d_in[26];
    const float* hbond = (const float*)d_in[27];
    const float* hydro = (const float*)d_in[28];
    const float* vdwc  = (const float*)d_in[29];
    const float* rotc  = (const float*)d_in[30];

    float* p = (float*)d_ws;
    float* g    = p; p += (size_t)ROWS * D;
    float* hb0  = p; p += (size_t)ROWS * D;
    float* hb1  = p; p += (size_t)ROWS * D;
    float* hA0  = p; p += (size_t)ROWS * D;
    float* hA1  = p; p += (size_t)ROWS * D;
    float* svals = p; p += CSR_ELEMS;
    float2* rowstat = (float2*)p; p += 2 * (size_t)ROWS;
    unsigned short* csr = (unsigned short*)p;
    int* nnz = (int*)(csr + CSR_ELEMS);
    float* aA = hb1;   // dead after k_Ssp(2)/k_hgp gather (both use buf0)
    float* aB = hA1;
    float* outp = (float*)d_out;

    k_csr<<<ROWS / 4, 256, 0, stream>>>(adj1, adj2, csr, nnz, outp);
    k_h0<<<ROWS / 16, 256, 0, stream>>>(h1, h2, nodeW, gatW, gatb, gatA, g, hb0, hA0);

    // layer 0
    k_Ssp<<<ROWS, 128, 0, stream>>>(hb0, hA0, csr, nnz, svals, rowstat);
    k_hgh<<<ROWS / 16, 256, 0, stream>>>(hb0, g, svals, rowstat, csr, nnz,
                                         gateW, gateb,
                                         gatW + (size_t)1 * D * D, gatb + D,
                                         gatA + (size_t)1 * D * D, hb1, hA1);
    // layer 1
    k_Ssp<<<ROWS, 128, 0, stream>>>(hb1, hA1, csr, nnz, svals, rowstat);
    k_hgh<<<ROWS / 16, 256, 0, stream>>>(hb1, g, svals, rowstat, csr, nnz,
                                         gateW + 2 * D, gateb + 1,
                                         gatW + (size_t)2 * D * D, gatb + 2 * D,
                                         gatA + (size_t)2 * D * D, hb0, hA0);
    // layer 2
    k_Ssp<<<ROWS, 128, 0, stream>>>(hb0, hA0, csr, nnz, svals, rowstat);
    k_hgp<<<ROWS / 16, 256, 0, stream>>>(hb0, g, svals, rowstat, csr, nnz,
                                         gateW + 4 * D, gateb + 2,
                                         vA_W1, vB_W1, vA_b1, vB_b1, aA, aB);

    k_pairz<<<dim3(64, NB), 256, 0, stream>>>(aA, aB, vA_W2, vB_W2, vA_b2, vB_b2,
                                              pos1, pos2, vr1, vr2, nm1, nm2, A_int,
                                              rotor, duff, hbond, hydro, vdwc, rotc,
                                              outp);
}

// Round 8
// 289.816 us; speedup vs baseline: 1.5322x; 1.5322x over previous
//
#include <hip/hip_runtime.h>
#include <math.h>

#define D 128
#define NB 8
#define NN1 128
#define NN2 512
#define ROWS1 (NB * NN1)          // 1024
#define ROWS2 (NB * NN2)          // 4096
#define ROWS (ROWS1 + ROWS2)      // 5120
#define CAP1 96
#define CAP2 160
#define CSR_ELEMS ((size_t)ROWS1 * CAP1 + (size_t)ROWS2 * CAP2)

__device__ __forceinline__ void resolve_row(int row, int& base_row, size_t& cbase,
                                            int& N) {
    if (row < ROWS1) {
        base_row = row & ~127;
        cbase = (size_t)row * CAP1;
        N = NN1;
    } else {
        int r = row - ROWS1;
        base_row = ROWS1 + (r & ~511);
        cbase = (size_t)ROWS1 * CAP1 + (size_t)r * CAP2;
        N = NN2;
    }
}

// XCD swizzle: all blocks for batch b have blockIdx%8==b so the batch's
// working set stays in one XCD's L2 (writers and readers alike).
__device__ __forceinline__ int swiz_row(int bid) {      // 5120 row blocks
    int batch = bid & 7, idx = bid >> 3;                // idx in [0,640)
    return (idx < NN1) ? batch * NN1 + idx
                       : ROWS1 + batch * NN2 + (idx - NN1);
}
__device__ __forceinline__ int swiz_row16(int bid) {    // 320 16-row blocks
    int batch = bid & 7, gi = bid >> 3;                 // gi in [0,40)
    return (gi < 8) ? batch * NN1 + gi * 16
                    : ROWS1 + batch * NN2 + (gi - 8) * 16;
}

// ---------------- CSR build (4 waves = 4 rows / block) + out zero ----------
__global__ __launch_bounds__(256) void k_csr(const float* __restrict__ adj1,
                                             const float* __restrict__ adj2,
                                             unsigned short* __restrict__ csr,
                                             int* __restrict__ nnz,
                                             float* __restrict__ out) {
    int t = threadIdx.x;
    if (blockIdx.x == 0 && t < NB * 5) out[t] = 0.f;
    int batch = blockIdx.x & 7, gi = blockIdx.x >> 3;   // gi in [0,160)
    int rowbase = (gi < 32) ? batch * NN1 + gi * 4
                            : ROWS1 + batch * NN2 + (gi - 32) * 4;
    int row = rowbase + (t >> 6);
    int lane = t & 63;
    int base_row, N;
    size_t cbase;
    resolve_row(row, base_row, cbase, N);
    int cap = (row < ROWS1) ? CAP1 : CAP2;
    const float* arow = (row < ROWS1) ? adj1 + (size_t)row * NN1
                                      : adj2 + (size_t)(row - ROWS1) * NN2;
    int cnt = 0;
    for (int c0 = 0; c0 < N; c0 += 64) {
        float v = arow[c0 + lane];
        unsigned long long m = __ballot(v > 0.f);
        int rank = __popcll(m & ((1ull << lane) - 1ull));
        if (v > 0.f && cnt + rank < cap)
            csr[cbase + cnt + rank] = (unsigned short)(c0 + lane);
        cnt += __popcll(m);
    }
    if (lane == 0) nnz[row] = cnt < cap ? cnt : cap;
}

// ---------------- node embed: g = h_in @ node_W (swizzled rows) ------------
__global__ __launch_bounds__(128) void k_embed(const float* __restrict__ h1,
                                               const float* __restrict__ h2,
                                               const float* __restrict__ W,
                                               float* __restrict__ g) {
    int row = swiz_row(blockIdx.x);
    int t = threadIdx.x;
    const float* src = (row < ROWS1) ? h1 + (size_t)row * 54
                                     : h2 + (size_t)(row - ROWS1) * 54;
    __shared__ float xr[56];
    if (t < 54) xr[t] = src[t];
    __syncthreads();
    float a0 = 0.f, a1 = 0.f;
#pragma unroll
    for (int k = 0; k < 54; k += 2) {
        a0 += xr[k] * W[k * D + t];
        if (k + 1 < 54) a1 += xr[k + 1] * W[(k + 1) * D + t];
    }
    g[(size_t)row * D + t] = a0 + a1;
}

// ---------------- h = g@W + b ; hA = h@A  (16 rows / block, swizzled) ------
__global__ __launch_bounds__(256) void k_h(const float* __restrict__ g,
                                           const float* __restrict__ W,
                                           const float* __restrict__ bias,
                                           const float* __restrict__ A,
                                           float* __restrict__ h, float* __restrict__ hA) {
    int row0 = swiz_row16(blockIdx.x);
    int t = threadIdx.x;
    int d = t & 127, rh = t >> 7;
    __shared__ float xs[16][D];
    __shared__ float hs[16][D];
    {
        int r = t >> 4, c = (t & 15) * 8;
        *(float4*)&xs[r][c] = *(const float4*)&g[((size_t)row0 + r) * D + c];
        *(float4*)&xs[r][c + 4] = *(const float4*)&g[((size_t)row0 + r) * D + c + 4];
    }
    __syncthreads();
    float bv = bias[d];
    float acc[8];
#pragma unroll
    for (int u = 0; u < 8; ++u) acc[u] = bv;
    for (int k0 = 0; k0 < D; k0 += 4) {
        float w0 = W[(k0 + 0) * D + d];
        float w1 = W[(k0 + 1) * D + d];
        float w2 = W[(k0 + 2) * D + d];
        float w3 = W[(k0 + 3) * D + d];
#pragma unroll
        for (int u = 0; u < 8; ++u) {
            float4 xv = *(const float4*)&xs[rh * 8 + u][k0];
            acc[u] += xv.x * w0 + xv.y * w1 + xv.z * w2 + xv.w * w3;
        }
    }
#pragma unroll
    for (int u = 0; u < 8; ++u) {
        int r = rh * 8 + u;
        h[((size_t)row0 + r) * D + d] = acc[u];
        hs[r][d] = acc[u];
    }
    __syncthreads();
    float acc2[8];
#pragma unroll
    for (int u = 0; u < 8; ++u) acc2[u] = 0.f;
    for (int k0 = 0; k0 < D; k0 += 4) {
        float w0 = A[(k0 + 0) * D + d];
        float w1 = A[(k0 + 1) * D + d];
        float w2 = A[(k0 + 2) * D + d];
        float w3 = A[(k0 + 3) * D + d];
#pragma unroll
        for (int u = 0; u < 8; ++u) {
            float4 xv = *(const float4*)&hs[rh * 8 + u][k0];
            acc2[u] += xv.x * w0 + xv.y * w1 + xv.z * w2 + xv.w * w3;
        }
    }
#pragma unroll
    for (int u = 0; u < 8; ++u)
        hA[((size_t)row0 + rh * 8 + u) * D + d] = acc2[u];
}

// ---- sparse S row + softmax stats (swizzled rows) ----
__global__ __launch_bounds__(128) void k_Ssp(const float* __restrict__ h,
                                             const float* __restrict__ hA,
                                             const unsigned short* __restrict__ csr,
                                             const int* __restrict__ nnz,
                                             float* __restrict__ svals,
                                             float2* __restrict__ rowstat) {
    int row = swiz_row(blockIdx.x);
    int t = threadIdx.x;
    int base_row, N;
    size_t cbase;
    resolve_row(row, base_row, cbase, N);
    int n = nnz[row];
    int grp = t >> 4, u = t & 15;
    const float* hrow = h + (size_t)row * D + u * 8;
    const float* hArow = hA + (size_t)row * D + u * 8;
    float4 hi0 = *(const float4*)&hrow[0], hi1 = *(const float4*)&hrow[4];
    float4 ai0 = *(const float4*)&hArow[0], ai1 = *(const float4*)&hArow[4];
    __shared__ float sv[CAP2];
    for (int s0 = 0; s0 < n; s0 += 16) {
        int sa = s0 + grp;
        int sb = sa + 8;
        float pa = 0.f, pb = 0.f;
        if (sa < n) {
            int jrow = base_row + csr[cbase + sa];
            const float* hj = h + (size_t)jrow * D + u * 8;
            const float* aj = hA + (size_t)jrow * D + u * 8;
            float4 hj0 = *(const float4*)&hj[0], hj1 = *(const float4*)&hj[4];
            float4 aj0 = *(const float4*)&aj[0], aj1 = *(const float4*)&aj[4];
            pa = hi0.x * aj0.x + hi0.y * aj0.y + hi0.z * aj0.z + hi0.w * aj0.w +
                 hi1.x * aj1.x + hi1.y * aj1.y + hi1.z * aj1.z + hi1.w * aj1.w +
                 ai0.x * hj0.x + ai0.y * hj0.y + ai0.z * hj0.z + ai0.w * hj0.w +
                 ai1.x * hj1.x + ai1.y * hj1.y + ai1.z * hj1.z + ai1.w * hj1.w;
        }
        if (sb < n) {
            int jrow = base_row + csr[cbase + sb];
            const float* hj = h + (size_t)jrow * D + u * 8;
            const float* aj = hA + (size_t)jrow * D + u * 8;
            float4 hj0 = *(const float4*)&hj[0], hj1 = *(const float4*)&hj[4];
            float4 aj0 = *(const float4*)&aj[0], aj1 = *(const float4*)&aj[4];
            pb = hi0.x * aj0.x + hi0.y * aj0.y + hi0.z * aj0.z + hi0.w * aj0.w +
                 hi1.x * aj1.x + hi1.y * aj1.y + hi1.z * aj1.z + hi1.w * aj1.w +
                 ai0.x * hj0.x + ai0.y * hj0.y + ai0.z * hj0.z + ai0.w * hj0.w +
                 ai1.x * hj1.x + ai1.y * hj1.y + ai1.z * hj1.z + ai1.w * hj1.w;
        }
#pragma unroll
        for (int o = 8; o > 0; o >>= 1) {
            pa += __shfl_xor(pa, o);
            pb += __shfl_xor(pb, o);
        }
        if (u == 0) {
            if (sa < n) sv[sa] = pa;
            if (sb < n) sv[sb] = pb;
        }
    }
    __syncthreads();
    if (t < 64) {
        float m = -3.4e38f;
        for (int s = t; s < n; s += 64) m = fmaxf(m, sv[s]);
#pragma unroll
        for (int o = 32; o > 0; o >>= 1) m = fmaxf(m, __shfl_xor(m, o));
        float sum = 0.f;
        for (int s = t; s < n; s += 64) sum += expf(sv[s] - m);
#pragma unroll
        for (int o = 32; o > 0; o >>= 1) sum += __shfl_xor(sum, o);
        if (t == 0) rowstat[row] = make_float2(m, 1.f / sum);
    }
    for (int s = t; s < n; s += 128) svals[cbase + s] = sv[s];
}

// ------- h_prime via symmetry + gate (128 thr, 8-deep ILP, swizzled) -------
__global__ __launch_bounds__(128) void k_hpgate(const float* __restrict__ hbuf,
                                                float* __restrict__ g,
                                                const float* __restrict__ svals,
                                                const float2* __restrict__ rowstat,
                                                const unsigned short* __restrict__ csr,
                                                const int* __restrict__ nnz,
                                                const float* __restrict__ gW,
                                                const float* __restrict__ gb) {
    int row = swiz_row(blockIdx.x);
    int d = threadIdx.x;
    int base_row, N;
    size_t cbase;
    resolve_row(row, base_row, cbase, N);
    int n = nnz[row];
    __shared__ float avals[CAP2];
    __shared__ int aidx[CAP2];
    __shared__ float red[128];
    for (int s = d; s < n; s += 128) {
        int jrow = base_row + csr[cbase + s];
        float2 st = rowstat[jrow];
        avals[s] = expf(svals[cbase + s] - st.x) * st.y;
        aidx[s] = jrow;
    }
    __syncthreads();
    float a[8];
#pragma unroll
    for (int u = 0; u < 8; ++u) a[u] = 0.f;
    int s = 0;
    for (; s + 8 <= n; s += 8) {
#pragma unroll
        for (int u = 0; u < 8; ++u)
            a[u] += avals[s + u] * hbuf[(size_t)aidx[s + u] * D + d];
    }
    for (; s < n; ++s) a[0] += avals[s] * hbuf[(size_t)aidx[s] * D + d];
    float hv = fmaxf(((a[0] + a[1]) + (a[2] + a[3])) + ((a[4] + a[5]) + (a[6] + a[7])),
                     0.f);
    float xv = g[(size_t)row * D + d];
    red[d] = xv * gW[d] + hv * gW[D + d];
    __syncthreads();
    for (int o = 64; o > 0; o >>= 1) {
        if (d < o) red[d] += red[d + o];
        __syncthreads();
    }
    float c = 1.f / (1.f + expf(-(red[0] + gb[0])));
    g[(size_t)row * D + d] = c * xv + (1.f - c) * hv;
}

// ------- pair-MLP precompute (16 rows / block, swizzled) -------------------
__global__ __launch_bounds__(256) void k_pairpre(const float* __restrict__ g,
                                                 const float* __restrict__ WA,
                                                 const float* __restrict__ WB,
                                                 const float* __restrict__ bA,
                                                 const float* __restrict__ bB,
                                                 float* __restrict__ aA,
                                                 float* __restrict__ aB) {
    int row0 = swiz_row16(blockIdx.x);
    int t = threadIdx.x;
    int d = t & 127, rh = t >> 7;
    int g2 = (row0 >= ROWS1);
    const float* WAp = g2 ? WA + D * D : WA;
    const float* WBp = g2 ? WB + D * D : WB;
    __shared__ float xs[16][D];
    {
        int r = t >> 4, c = (t & 15) * 8;
        *(float4*)&xs[r][c] = *(const float4*)&g[((size_t)row0 + r) * D + c];
        *(float4*)&xs[r][c + 4] = *(const float4*)&g[((size_t)row0 + r) * D + c + 4];
    }
    __syncthreads();
    float bvA = g2 ? 0.f : bA[d];
    float bvB = g2 ? 0.f : bB[d];
    float accA[8], accB[8];
#pragma unroll
    for (int u = 0; u < 8; ++u) { accA[u] = bvA; accB[u] = bvB; }
    for (int k0 = 0; k0 < D; k0 += 4) {
        float wa0 = WAp[(k0 + 0) * D + d], wa1 = WAp[(k0 + 1) * D + d];
        float wa2 = WAp[(k0 + 2) * D + d], wa3 = WAp[(k0 + 3) * D + d];
        float wb0 = WBp[(k0 + 0) * D + d], wb1 = WBp[(k0 + 1) * D + d];
        float wb2 = WBp[(k0 + 2) * D + d], wb3 = WBp[(k0 + 3) * D + d];
#pragma unroll
        for (int u = 0; u < 8; ++u) {
            float4 xv = *(const float4*)&xs[rh * 8 + u][k0];
            accA[u] += xv.x * wa0 + xv.y * wa1 + xv.z * wa2 + xv.w * wa3;
            accB[u] += xv.x * wb0 + xv.y * wb1 + xv.z * wb2 + xv.w * wb3;
        }
    }
#pragma unroll
    for (int u = 0; u < 8; ++u) {
        int r = rh * 8 + u;
        aA[((size_t)row0 + r) * D + d] = accA[u];
        aB[((size_t)row0 + r) * D + d] = accB[u];
    }
}

// --------- fused pair z-GEMM + energies + atomic output (1D swizzled) ------
__global__ __launch_bounds__(256) void k_pairz(
    const float* __restrict__ aA, const float* __restrict__ aB,
    const float* __restrict__ w2A, const float* __restrict__ w2B,
    const float* __restrict__ b2A, const float* __restrict__ b2B,
    const float* __restrict__ pos1, const float* __restrict__ pos2,
    const float* __restrict__ vr1, const float* __restrict__ vr2,
    const float* __restrict__ nm1, const float* __restrict__ nm2,
    const float* __restrict__ A_int, const float* __restrict__ rotor,
    const float* __restrict__ duff, const float* __restrict__ hbond,
    const float* __restrict__ hydro, const float* __restrict__ vdwc,
    const float* __restrict__ rotc, float* __restrict__ out) {
    int b = blockIdx.x & 7;                 // XCD-affine batch
    int tile = blockIdx.x >> 3;             // 64 tiles
    int itile = tile >> 4, jtile = tile & 15;
    int i0 = itile * 32, j0 = jtile * 32;
    int t = threadIdx.x;
    int tx = t & 15, ty = t >> 4;
    __shared__ float A1a[32][20], A1b[32][20], A2a[32][20], A2b[32][20];
    __shared__ float w2As[128], w2Bs[128];
    __shared__ float zAs[32][33], zBs[32][33];
    __shared__ float redc[8][4];
    if (t < 128) { w2As[t] = w2A[t]; w2Bs[t] = w2B[t]; }
    float zA[2][2] = {{0.f, 0.f}, {0.f, 0.f}};
    float zB[2][2] = {{0.f, 0.f}, {0.f, 0.f}};
    int half = t >> 7, idx = t & 127;
    int sr = idx >> 2, sc = (idx & 3) * 4;
    size_t grow = half ? (size_t)(ROWS1 + b * NN2 + j0 + sr)
                       : (size_t)(b * NN1 + i0 + sr);
    for (int hc = 0; hc < D; hc += 16) {
        __syncthreads();
        float4 va = *(const float4*)&aA[grow * D + hc + sc];
        float4 vb = *(const float4*)&aB[grow * D + hc + sc];
        if (half) { *(float4*)&A2a[sr][sc] = va; *(float4*)&A2b[sr][sc] = vb; }
        else      { *(float4*)&A1a[sr][sc] = va; *(float4*)&A1b[sr][sc] = vb; }
        __syncthreads();
#pragma unroll
        for (int hh = 0; hh < 16; hh += 4) {
            float4 wA = *(const float4*)&w2As[hc + hh];
            float4 wB = *(const float4*)&w2Bs[hc + hh];
            float4 xA0 = *(const float4*)&A1a[ty][hh];
            float4 xA1 = *(const float4*)&A1a[ty + 16][hh];
            float4 xB0 = *(const float4*)&A1b[ty][hh];
            float4 xB1 = *(const float4*)&A1b[ty + 16][hh];
            float4 yA0 = *(const float4*)&A2a[tx][hh];
            float4 yA1 = *(const float4*)&A2a[tx + 16][hh];
            float4 yB0 = *(const float4*)&A2b[tx][hh];
            float4 yB1 = *(const float4*)&A2b[tx + 16][hh];
#define RD4(xx, yy, ww) (fmaxf(xx.x + yy.x, 0.f) * ww.x + fmaxf(xx.y + yy.y, 0.f) * ww.y + \
                         fmaxf(xx.z + yy.z, 0.f) * ww.z + fmaxf(xx.w + yy.w, 0.f) * ww.w)
            zA[0][0] += RD4(xA0, yA0, wA); zA[0][1] += RD4(xA0, yA1, wA);
            zA[1][0] += RD4(xA1, yA0, wA); zA[1][1] += RD4(xA1, yA1, wA);
            zB[0][0] += RD4(xB0, yB0, wB); zB[0][1] += RD4(xB0, yB1, wB);
            zB[1][0] += RD4(xB1, yB0, wB); zB[1][1] += RD4(xB1, yB1, wB);
#undef RD4
        }
    }
#pragma unroll
    for (int u = 0; u < 2; ++u)
#pragma unroll
        for (int v = 0; v < 2; ++v) {
            zAs[ty + 16 * u][tx + 16 * v] = zA[u][v];
            zBs[ty + 16 * u][tx + 16 * v] = zB[u][v];
        }
    __syncthreads();
    int j2 = t & 31, ig = t >> 5;
    int jg = j0 + j2;
    size_t j_off = (size_t)b * NN2 + jg;
    float p2x = pos2[j_off * 3 + 0], p2y = pos2[j_off * 3 + 1], p2z = pos2[j_off * 3 + 2];
    float r2 = vr2[j_off], m2 = nm2[j_off];
    float zb2A = b2A[0], zb2B = b2B[0];
    float eV[4], e1[4], e2[4], eH[4];
#pragma unroll
    for (int ii = 0; ii < 4; ++ii) {
        int il = ig * 4 + ii;
        int iglob = i0 + il;
        size_t i_off = (size_t)b * NN1 + iglob;
        float zAv = zAs[il][j2] + zb2A;
        float zBv = zBs[il][j2] + zb2B;
        float dx = pos1[i_off * 3 + 0] - p2x;
        float dy = pos1[i_off * 3 + 1] - p2y;
        float dz = pos1[i_off * 3 + 2] - p2z;
        float dm = sqrtf(dx * dx + dy * dy + dz * dz + 1e-10f);
        if (dm < 0.5f) dm = 1e10f;
        float A_w = 1.f / (1.f + expf(-zAv));
        float B_w = tanhf(zBv) * 0.2f;
        float dm0 = vr1[i_off] + r2 + B_w;
        float dm0s = (dm0 < 1e-4f) ? 1.f : dm0;
        float rr = dm0s / dm;
        float rr2 = rr * rr;
        float rN = rr2 * rr2 * rr2;
        float evdw = fminf(rN * rN - 2.f * rN, 100.f);
        float mask = nm1[i_off] * m2;
        float Aamp = A_w * (0.0356f - 0.0178f) + 0.0178f;
        eV[ii] = Aamp * evdw * mask;
        float dmd = dm - dm0;
        size_t abase = (((size_t)b * 8) * NN1 + iglob) * NN2 + jg;
        float Ai1 = A_int[abase + (size_t)1 * NN1 * NN2];
        float Ai6 = A_int[abase + (size_t)6 * NN1 * NN2];
        float Ai7 = A_int[abase + (size_t)7 * NN1 * NN2];
        e1[ii] = fminf(fmaxf(dmd * Ai1 * (-1.f / 0.7f), 0.f), 1.f);
        e2[ii] = fminf(fmaxf(dmd * Ai7 * (-1.f / 0.7f), 0.f), 1.f);
        eH[ii] = fminf(fmaxf((1.5f - dmd) * Ai6, 0.f), 1.f);
    }
    float sV = (eV[0] + eV[1]) + (eV[2] + eV[3]);
    float s1 = (e1[0] + e1[1]) + (e1[2] + e1[3]);
    float s2 = (e2[0] + e2[1]) + (e2[2] + e2[3]);
    float sH = (eH[0] + eH[1]) + (eH[2] + eH[3]);
#pragma unroll
    for (int o = 16; o > 0; o >>= 1) {
        sV += __shfl_xor(sV, o);
        s1 += __shfl_xor(s1, o);
        s2 += __shfl_xor(s2, o);
        sH += __shfl_xor(sH, o);
    }
    if (j2 == 0) {
        redc[ig][0] = sV; redc[ig][1] = s1; redc[ig][2] = s2; redc[ig][3] = sH;
    }
    __syncthreads();
    if (t < 4) {
        float v = 0.f;
#pragma unroll
        for (int gg = 0; gg < 8; ++gg) v += redc[gg][t];
        float scl = 1.f / (1.f + rotc[0] * rotc[0] * rotor[b]);
        float coef;
        if (t == 0) coef = scl;
        else if (t == 3) coef = -hydro[0] * hydro[0] * scl;
        else coef = -hbond[0] * hbond[0] * scl;
        atomicAdd(&out[b * 5 + t], v * coef);
    }
    if (t == 4 && tile == 0) {
        float scl = 1.f / (1.f + rotc[0] * rotc[0] * rotor[b]);
        atomicAdd(&out[b * 5 + 4], duff[b] * vdwc[0] * vdwc[0] * scl);
    }
}

extern "C" void kernel_launch(void* const* d_in, const int* in_sizes, int n_in,
                              void* d_out, int out_size, void* d_ws, size_t ws_size,
                              hipStream_t stream) {
    const float* h1    = (const float*)d_in[0];
    const float* adj1  = (const float*)d_in[1];
    const float* h2    = (const float*)d_in[2];
    const float* adj2  = (const float*)d_in[3];
    const float* A_int = (const float*)d_in[4];
    const float* pos1  = (const float*)d_in[5];
    const float* pos2  = (const float*)d_in[6];
    const float* rotor = (const float*)d_in[7];
    const float* vr1   = (const float*)d_in[8];
    const float* vr2   = (const float*)d_in[9];
    const float* duff  = (const float*)d_in[10];
    const float* nm1   = (const float*)d_in[11];
    const float* nm2   = (const float*)d_in[12];
    const float* nodeW = (const float*)d_in[13];
    const float* gatW  = (const float*)d_in[14];
    const float* gatb  = (const float*)d_in[15];
    const float* gatA  = (const float*)d_in[16];
    const float* gateW = (const float*)d_in[17];
    const float* gateb = (const float*)d_in[18];
    const float* vA_W1 = (const float*)d_in[19];
    const float* vA_b1 = (const float*)d_in[20];
    const float* vA_W2 = (const float*)d_in[21];
    const float* vA_b2 = (const float*)d_in[22];
    const float* vB_W1 = (const float*)d_in[23];
    const float* vB_b1 = (const float*)d_in[24];
    const float* vB_W2 = (const float*)d_in[25];
    const float* vB_b2 = (const float*)d_in[26];
    const float* hbond = (const float*)d_in[27];
    const float* hydro = (const float*)d_in[28];
    const float* vdwc  = (const float*)d_in[29];
    const float* rotc  = (const float*)d_in[30];

    float* p = (float*)d_ws;
    float* g     = p; p += (size_t)ROWS * D;
    float* hbuf  = p; p += (size_t)ROWS * D;
    float* hAbuf = p; p += (size_t)ROWS * D;
    float* svals = p; p += CSR_ELEMS;
    float2* rowstat = (float2*)p; p += 2 * (size_t)ROWS;
    unsigned short* csr = (unsigned short*)p;
    int* nnz = (int*)(csr + CSR_ELEMS);
    float* aA = hbuf;   // aliases: hbuf/hAbuf dead after last k_hpgate
    float* aB = hAbuf;
    float* outp = (float*)d_out;

    k_csr<<<ROWS / 4, 256, 0, stream>>>(adj1, adj2, csr, nnz, outp);
    k_embed<<<ROWS, 128, 0, stream>>>(h1, h2, nodeW, g);

    for (int l = 0; l < 3; ++l) {
        const float* W  = gatW  + (size_t)l * D * D;
        const float* bb = gatb  + (size_t)l * D;
        const float* A  = gatA  + (size_t)l * D * D;
        const float* gW = gateW + (size_t)l * 2 * D;
        const float* gb = gateb + l;
        k_h<<<ROWS / 16, 256, 0, stream>>>(g, W, bb, A, hbuf, hAbuf);
        k_Ssp<<<ROWS, 128, 0, stream>>>(hbuf, hAbuf, csr, nnz, svals, rowstat);
        k_hpgate<<<ROWS, 128, 0, stream>>>(hbuf, g, svals, rowstat, csr, nnz, gW, gb);
    }

    k_pairpre<<<ROWS / 16, 256, 0, stream>>>(g, vA_W1, vB_W1, vA_b1, vB_b1, aA, aB);
    k_pairz<<<512, 256, 0, stream>>>(aA, aB, vA_W2, vB_W2, vA_b2, vB_b2,
                                     pos1, pos2, vr1, vr2, nm1, nm2, A_int,
                                     rotor, duff, hbond, hydro, vdwc, rotc, outp);
}

// Round 9
// 285.404 us; speedup vs baseline: 1.5559x; 1.0155x over previous
//
#include <hip/hip_runtime.h>
#include <hip/hip_fp16.h>
#include <math.h>

#define D 128
#define NB 8
#define NN1 128
#define NN2 512
#define ROWS1 (NB * NN1)          // 1024
#define ROWS2 (NB * NN2)          // 4096
#define ROWS (ROWS1 + ROWS2)      // 5120
#define CAP1 96
#define CAP2 160
#define CSR_ELEMS ((size_t)ROWS1 * CAP1 + (size_t)ROWS2 * CAP2)

typedef __half HT;

__device__ __forceinline__ void resolve_row(int row, int& base_row, size_t& cbase,
                                            int& N) {
    if (row < ROWS1) {
        base_row = row & ~127;
        cbase = (size_t)row * CAP1;
        N = NN1;
    } else {
        int r = row - ROWS1;
        base_row = ROWS1 + (r & ~511);
        cbase = (size_t)ROWS1 * CAP1 + (size_t)r * CAP2;
        N = NN2;
    }
}

// XCD swizzle: all blocks for batch b have blockIdx%8==b (validated R8: -23us).
__device__ __forceinline__ int swiz_row(int bid) {      // 5120 row blocks
    int batch = bid & 7, idx = bid >> 3;
    return (idx < NN1) ? batch * NN1 + idx
                       : ROWS1 + batch * NN2 + (idx - NN1);
}
__device__ __forceinline__ int swiz_row16(int bid) {    // 320 16-row blocks
    int batch = bid & 7, gi = bid >> 3;
    return (gi < 8) ? batch * NN1 + gi * 16
                    : ROWS1 + batch * NN2 + (gi - 8) * 16;
}

// load 8 halves (16B) -> 8 floats
__device__ __forceinline__ void load8h(const HT* p, float* o) {
    float4 raw = *(const float4*)p;
    const __half2* h2 = (const __half2*)&raw;
    float2 f0 = __half22float2(h2[0]);
    float2 f1 = __half22float2(h2[1]);
    float2 f2 = __half22float2(h2[2]);
    float2 f3 = __half22float2(h2[3]);
    o[0] = f0.x; o[1] = f0.y; o[2] = f1.x; o[3] = f1.y;
    o[4] = f2.x; o[5] = f2.y; o[6] = f3.x; o[7] = f3.y;
}

// ------- fused: node embed (128 thr) + CSR build (wave 0) + out zero -------
__global__ __launch_bounds__(128) void k_csrembed(
    const float* __restrict__ h1, const float* __restrict__ h2,
    const float* __restrict__ adj1, const float* __restrict__ adj2,
    const float* __restrict__ W, float* __restrict__ g,
    unsigned short* __restrict__ csr, int* __restrict__ nnz,
    float* __restrict__ out) {
    int row = swiz_row(blockIdx.x);
    int t = threadIdx.x;
    if (blockIdx.x == 0 && t < NB * 5) out[t] = 0.f;
    const float* src = (row < ROWS1) ? h1 + (size_t)row * 54
                                     : h2 + (size_t)(row - ROWS1) * 54;
    __shared__ float xr[56];
    if (t < 54) xr[t] = src[t];
    __syncthreads();
    float a0 = 0.f, a1 = 0.f;
#pragma unroll
    for (int k = 0; k < 54; k += 2) {
        a0 += xr[k] * W[k * D + t];
        if (k + 1 < 54) a1 += xr[k + 1] * W[(k + 1) * D + t];
    }
    g[(size_t)row * D + t] = a0 + a1;

    if (t < 64) {
        int base_row, N;
        size_t cbase;
        resolve_row(row, base_row, cbase, N);
        int cap = (row < ROWS1) ? CAP1 : CAP2;
        const float* arow = (row < ROWS1) ? adj1 + (size_t)row * NN1
                                          : adj2 + (size_t)(row - ROWS1) * NN2;
        int cnt = 0;
        for (int c0 = 0; c0 < N; c0 += 64) {
            float v = arow[c0 + t];
            unsigned long long m = __ballot(v > 0.f);
            int rank = __popcll(m & ((1ull << t) - 1ull));
            if (v > 0.f && cnt + rank < cap)
                csr[cbase + cnt + rank] = (unsigned short)(c0 + t);
            cnt += __popcll(m);
        }
        if (t == 0) nnz[row] = cnt < cap ? cnt : cap;
    }
}

// ------ h = g@W + b ; hA = h@A  (16 rows / block, swizzled, fp16 out) ------
__global__ __launch_bounds__(256) void k_h(const float* __restrict__ g,
                                           const float* __restrict__ W,
                                           const float* __restrict__ bias,
                                           const float* __restrict__ A,
                                           HT* __restrict__ h, HT* __restrict__ hA) {
    int row0 = swiz_row16(blockIdx.x);
    int t = threadIdx.x;
    int d = t & 127, rh = t >> 7;
    __shared__ float xs[16][D];
    __shared__ float hs[16][D];
    {
        int r = t >> 4, c = (t & 15) * 8;
        *(float4*)&xs[r][c] = *(const float4*)&g[((size_t)row0 + r) * D + c];
        *(float4*)&xs[r][c + 4] = *(const float4*)&g[((size_t)row0 + r) * D + c + 4];
    }
    __syncthreads();
    float bv = bias[d];
    float acc[8];
#pragma unroll
    for (int u = 0; u < 8; ++u) acc[u] = bv;
    for (int k0 = 0; k0 < D; k0 += 4) {
        float w0 = W[(k0 + 0) * D + d];
        float w1 = W[(k0 + 1) * D + d];
        float w2 = W[(k0 + 2) * D + d];
        float w3 = W[(k0 + 3) * D + d];
#pragma unroll
        for (int u = 0; u < 8; ++u) {
            float4 xv = *(const float4*)&xs[rh * 8 + u][k0];
            acc[u] += xv.x * w0 + xv.y * w1 + xv.z * w2 + xv.w * w3;
        }
    }
#pragma unroll
    for (int u = 0; u < 8; ++u) {
        int r = rh * 8 + u;
        h[((size_t)row0 + r) * D + d] = __float2half(acc[u]);
        hs[r][d] = acc[u];
    }
    __syncthreads();
    float acc2[8];
#pragma unroll
    for (int u = 0; u < 8; ++u) acc2[u] = 0.f;
    for (int k0 = 0; k0 < D; k0 += 4) {
        float w0 = A[(k0 + 0) * D + d];
        float w1 = A[(k0 + 1) * D + d];
        float w2 = A[(k0 + 2) * D + d];
        float w3 = A[(k0 + 3) * D + d];
#pragma unroll
        for (int u = 0; u < 8; ++u) {
            float4 xv = *(const float4*)&hs[rh * 8 + u][k0];
            acc2[u] += xv.x * w0 + xv.y * w1 + xv.z * w2 + xv.w * w3;
        }
    }
#pragma unroll
    for (int u = 0; u < 8; ++u)
        hA[((size_t)row0 + rh * 8 + u) * D + d] = __float2half(acc2[u]);
}

// ---- sparse S row + softmax stats (fp16 gathers: 1 load/row/buffer) ----
__global__ __launch_bounds__(128) void k_Ssp(const HT* __restrict__ h,
                                             const HT* __restrict__ hA,
                                             const unsigned short* __restrict__ csr,
                                             const int* __restrict__ nnz,
                                             float* __restrict__ svals,
                                             float2* __restrict__ rowstat) {
    int row = swiz_row(blockIdx.x);
    int t = threadIdx.x;
    int base_row, N;
    size_t cbase;
    resolve_row(row, base_row, cbase, N);
    int n = nnz[row];
    int grp = t >> 4, u = t & 15;   // 8 groups x 16 lanes; lane slice = u*8
    float hi[8], ai[8];
    load8h(h + (size_t)row * D + u * 8, hi);
    load8h(hA + (size_t)row * D + u * 8, ai);
    __shared__ float sv[CAP2];
    for (int s0 = 0; s0 < n; s0 += 16) {
        int sa = s0 + grp;
        int sb = sa + 8;
        float pa = 0.f, pb = 0.f;
        if (sa < n) {
            int jrow = base_row + csr[cbase + sa];
            float hj[8], aj[8];
            load8h(h + (size_t)jrow * D + u * 8, hj);
            load8h(hA + (size_t)jrow * D + u * 8, aj);
#pragma unroll
            for (int q = 0; q < 8; ++q) pa += hi[q] * aj[q] + ai[q] * hj[q];
        }
        if (sb < n) {
            int jrow = base_row + csr[cbase + sb];
            float hj[8], aj[8];
            load8h(h + (size_t)jrow * D + u * 8, hj);
            load8h(hA + (size_t)jrow * D + u * 8, aj);
#pragma unroll
            for (int q = 0; q < 8; ++q) pb += hi[q] * aj[q] + ai[q] * hj[q];
        }
#pragma unroll
        for (int o = 8; o > 0; o >>= 1) {
            pa += __shfl_xor(pa, o);
            pb += __shfl_xor(pb, o);
        }
        if (u == 0) {
            if (sa < n) sv[sa] = pa;
            if (sb < n) sv[sb] = pb;
        }
    }
    __syncthreads();
    if (t < 64) {
        float m = -3.4e38f;
        for (int s = t; s < n; s += 64) m = fmaxf(m, sv[s]);
#pragma unroll
        for (int o = 32; o > 0; o >>= 1) m = fmaxf(m, __shfl_xor(m, o));
        float sum = 0.f;
        for (int s = t; s < n; s += 64) sum += expf(sv[s] - m);
#pragma unroll
        for (int o = 32; o > 0; o >>= 1) sum += __shfl_xor(sum, o);
        if (t == 0) rowstat[row] = make_float2(m, 1.f / sum);
    }
    for (int s = t; s < n; s += 128) svals[cbase + s] = sv[s];
}

// ------- h_prime via symmetry + gate (fp16 gathers, 8-deep ILP) ------------
__global__ __launch_bounds__(128) void k_hpgate(const HT* __restrict__ hbuf,
                                                float* __restrict__ g,
                                                const float* __restrict__ svals,
                                                const float2* __restrict__ rowstat,
                                                const unsigned short* __restrict__ csr,
                                                const int* __restrict__ nnz,
                                                const float* __restrict__ gW,
                                                const float* __restrict__ gb) {
    int row = swiz_row(blockIdx.x);
    int d = threadIdx.x;
    int base_row, N;
    size_t cbase;
    resolve_row(row, base_row, cbase, N);
    int n = nnz[row];
    __shared__ float avals[CAP2];
    __shared__ int aidx[CAP2];
    __shared__ float red[128];
    for (int s = d; s < n; s += 128) {
        int jrow = base_row + csr[cbase + s];
        float2 st = rowstat[jrow];
        avals[s] = expf(svals[cbase + s] - st.x) * st.y;
        aidx[s] = jrow;
    }
    __syncthreads();
    float a[8];
#pragma unroll
    for (int u = 0; u < 8; ++u) a[u] = 0.f;
    int s = 0;
    for (; s + 8 <= n; s += 8) {
#pragma unroll
        for (int u = 0; u < 8; ++u)
            a[u] += avals[s + u] * __half2float(hbuf[(size_t)aidx[s + u] * D + d]);
    }
    for (; s < n; ++s)
        a[0] += avals[s] * __half2float(hbuf[(size_t)aidx[s] * D + d]);
    float hv = fmaxf(((a[0] + a[1]) + (a[2] + a[3])) + ((a[4] + a[5]) + (a[6] + a[7])),
                     0.f);
    float xv = g[(size_t)row * D + d];
    red[d] = xv * gW[d] + hv * gW[D + d];
    __syncthreads();
    for (int o = 64; o > 0; o >>= 1) {
        if (d < o) red[d] += red[d + o];
        __syncthreads();
    }
    float c = 1.f / (1.f + expf(-(red[0] + gb[0])));
    g[(size_t)row * D + d] = c * xv + (1.f - c) * hv;
}

// ------- pair-MLP precompute (16 rows / block, swizzled, fp32) -------------
__global__ __launch_bounds__(256) void k_pairpre(const float* __restrict__ g,
                                                 const float* __restrict__ WA,
                                                 const float* __restrict__ WB,
                                                 const float* __restrict__ bA,
                                                 const float* __restrict__ bB,
                                                 float* __restrict__ aA,
                                                 float* __restrict__ aB) {
    int row0 = swiz_row16(blockIdx.x);
    int t = threadIdx.x;
    int d = t & 127, rh = t >> 7;
    int g2 = (row0 >= ROWS1);
    const float* WAp = g2 ? WA + D * D : WA;
    const float* WBp = g2 ? WB + D * D : WB;
    __shared__ float xs[16][D];
    {
        int r = t >> 4, c = (t & 15) * 8;
        *(float4*)&xs[r][c] = *(const float4*)&g[((size_t)row0 + r) * D + c];
        *(float4*)&xs[r][c + 4] = *(const float4*)&g[((size_t)row0 + r) * D + c + 4];
    }
    __syncthreads();
    float bvA = g2 ? 0.f : bA[d];
    float bvB = g2 ? 0.f : bB[d];
    float accA[8], accB[8];
#pragma unroll
    for (int u = 0; u < 8; ++u) { accA[u] = bvA; accB[u] = bvB; }
    for (int k0 = 0; k0 < D; k0 += 4) {
        float wa0 = WAp[(k0 + 0) * D + d], wa1 = WAp[(k0 + 1) * D + d];
        float wa2 = WAp[(k0 + 2) * D + d], wa3 = WAp[(k0 + 3) * D + d];
        float wb0 = WBp[(k0 + 0) * D + d], wb1 = WBp[(k0 + 1) * D + d];
        float wb2 = WBp[(k0 + 2) * D + d], wb3 = WBp[(k0 + 3) * D + d];
#pragma unroll
        for (int u = 0; u < 8; ++u) {
            float4 xv = *(const float4*)&xs[rh * 8 + u][k0];
            accA[u] += xv.x * wa0 + xv.y * wa1 + xv.z * wa2 + xv.w * wa3;
            accB[u] += xv.x * wb0 + xv.y * wb1 + xv.z * wb2 + xv.w * wb3;
        }
    }
#pragma unroll
    for (int u = 0; u < 8; ++u) {
        int r = rh * 8 + u;
        aA[((size_t)row0 + r) * D + d] = accA[u];
        aB[((size_t)row0 + r) * D + d] = accB[u];
    }
}

// --------- fused pair z-GEMM + energies + atomic output (1D swizzled) ------
__global__ __launch_bounds__(256) void k_pairz(
    const float* __restrict__ aA, const float* __restrict__ aB,
    const float* __restrict__ w2A, const float* __restrict__ w2B,
    const float* __restrict__ b2A, const float* __restrict__ b2B,
    const float* __restrict__ pos1, const float* __restrict__ pos2,
    const float* __restrict__ vr1, const float* __restrict__ vr2,
    const float* __restrict__ nm1, const float* __restrict__ nm2,
    const float* __restrict__ A_int, const float* __restrict__ rotor,
    const float* __restrict__ duff, const float* __restrict__ hbond,
    const float* __restrict__ hydro, const float* __restrict__ vdwc,
    const float* __restrict__ rotc, float* __restrict__ out) {
    int b = blockIdx.x & 7;                 // XCD-affine batch
    int tile = blockIdx.x >> 3;             // 64 tiles
    int itile = tile >> 4, jtile = tile & 15;
    int i0 = itile * 32, j0 = jtile * 32;
    int t = threadIdx.x;
    int tx = t & 15, ty = t >> 4;
    __shared__ float A1a[32][20], A1b[32][20], A2a[32][20], A2b[32][20];
    __shared__ float w2As[128], w2Bs[128];
    __shared__ float zAs[32][33], zBs[32][33];
    __shared__ float redc[8][4];
    if (t < 128) { w2As[t] = w2A[t]; w2Bs[t] = w2B[t]; }
    float zA[2][2] = {{0.f, 0.f}, {0.f, 0.f}};
    float zB[2][2] = {{0.f, 0.f}, {0.f, 0.f}};
    int half = t >> 7, idx = t & 127;
    int sr = idx >> 2, sc = (idx & 3) * 4;
    size_t grow = half ? (size_t)(ROWS1 + b * NN2 + j0 + sr)
                       : (size_t)(b * NN1 + i0 + sr);
    for (int hc = 0; hc < D; hc += 16) {
        __syncthreads();
        float4 va = *(const float4*)&aA[grow * D + hc + sc];
        float4 vb = *(const float4*)&aB[grow * D + hc + sc];
        if (half) { *(float4*)&A2a[sr][sc] = va; *(float4*)&A2b[sr][sc] = vb; }
        else      { *(float4*)&A1a[sr][sc] = va; *(float4*)&A1b[sr][sc] = vb; }
        __syncthreads();
#pragma unroll
        for (int hh = 0; hh < 16; hh += 4) {
            float4 wA = *(const float4*)&w2As[hc + hh];
            float4 wB = *(const float4*)&w2Bs[hc + hh];
            float4 xA0 = *(const float4*)&A1a[ty][hh];
            float4 xA1 = *(const float4*)&A1a[ty + 16][hh];
            float4 xB0 = *(const float4*)&A1b[ty][hh];
            float4 xB1 = *(const float4*)&A1b[ty + 16][hh];
            float4 yA0 = *(const float4*)&A2a[tx][hh];
            float4 yA1 = *(const float4*)&A2a[tx + 16][hh];
            float4 yB0 = *(const float4*)&A2b[tx][hh];
            float4 yB1 = *(const float4*)&A2b[tx + 16][hh];
#define RD4(xx, yy, ww) (fmaxf(xx.x + yy.x, 0.f) * ww.x + fmaxf(xx.y + yy.y, 0.f) * ww.y + \
                         fmaxf(xx.z + yy.z, 0.f) * ww.z + fmaxf(xx.w + yy.w, 0.f) * ww.w)
            zA[0][0] += RD4(xA0, yA0, wA); zA[0][1] += RD4(xA0, yA1, wA);
            zA[1][0] += RD4(xA1, yA0, wA); zA[1][1] += RD4(xA1, yA1, wA);
            zB[0][0] += RD4(xB0, yB0, wB); zB[0][1] += RD4(xB0, yB1, wB);
            zB[1][0] += RD4(xB1, yB0, wB); zB[1][1] += RD4(xB1, yB1, wB);
#undef RD4
        }
    }
#pragma unroll
    for (int u = 0; u < 2; ++u)
#pragma unroll
        for (int v = 0; v < 2; ++v) {
            zAs[ty + 16 * u][tx + 16 * v] = zA[u][v];
            zBs[ty + 16 * u][tx + 16 * v] = zB[u][v];
        }
    __syncthreads();
    int j2 = t & 31, ig = t >> 5;
    int jg = j0 + j2;
    size_t j_off = (size_t)b * NN2 + jg;
    float p2x = pos2[j_off * 3 + 0], p2y = pos2[j_off * 3 + 1], p2z = pos2[j_off * 3 + 2];
    float r2 = vr2[j_off], m2 = nm2[j_off];
    float zb2A = b2A[0], zb2B = b2B[0];
    float eV[4], e1[4], e2[4], eH[4];
#pragma unroll
    for (int ii = 0; ii < 4; ++ii) {
        int il = ig * 4 + ii;
        int iglob = i0 + il;
        size_t i_off = (size_t)b * NN1 + iglob;
        float zAv = zAs[il][j2] + zb2A;
        float zBv = zBs[il][j2] + zb2B;
        float dx = pos1[i_off * 3 + 0] - p2x;
        float dy = pos1[i_off * 3 + 1] - p2y;
        float dz = pos1[i_off * 3 + 2] - p2z;
        float dm = sqrtf(dx * dx + dy * dy + dz * dz + 1e-10f);
        if (dm < 0.5f) dm = 1e10f;
        float A_w = 1.f / (1.f + expf(-zAv));
        float B_w = tanhf(zBv) * 0.2f;
        float dm0 = vr1[i_off] + r2 + B_w;
        float dm0s = (dm0 < 1e-4f) ? 1.f : dm0;
        float rr = dm0s / dm;
        float rr2 = rr * rr;
        float rN = rr2 * rr2 * rr2;
        float evdw = fminf(rN * rN - 2.f * rN, 100.f);
        float mask = nm1[i_off] * m2;
        float Aamp = A_w * (0.0356f - 0.0178f) + 0.0178f;
        eV[ii] = Aamp * evdw * mask;
        float dmd = dm - dm0;
        size_t abase = (((size_t)b * 8) * NN1 + iglob) * NN2 + jg;
        float Ai1 = A_int[abase + (size_t)1 * NN1 * NN2];
        float Ai6 = A_int[abase + (size_t)6 * NN1 * NN2];
        float Ai7 = A_int[abase + (size_t)7 * NN1 * NN2];
        e1[ii] = fminf(fmaxf(dmd * Ai1 * (-1.f / 0.7f), 0.f), 1.f);
        e2[ii] = fminf(fmaxf(dmd * Ai7 * (-1.f / 0.7f), 0.f), 1.f);
        eH[ii] = fminf(fmaxf((1.5f - dmd) * Ai6, 0.f), 1.f);
    }
    float sV = (eV[0] + eV[1]) + (eV[2] + eV[3]);
    float s1 = (e1[0] + e1[1]) + (e1[2] + e1[3]);
    float s2 = (e2[0] + e2[1]) + (e2[2] + e2[3]);
    float sH = (eH[0] + eH[1]) + (eH[2] + eH[3]);
#pragma unroll
    for (int o = 16; o > 0; o >>= 1) {
        sV += __shfl_xor(sV, o);
        s1 += __shfl_xor(s1, o);
        s2 += __shfl_xor(s2, o);
        sH += __shfl_xor(sH, o);
    }
    if (j2 == 0) {
        redc[ig][0] = sV; redc[ig][1] = s1; redc[ig][2] = s2; redc[ig][3] = sH;
    }
    __syncthreads();
    if (t < 4) {
        float v = 0.f;
#pragma unroll
        for (int gg = 0; gg < 8; ++gg) v += redc[gg][t];
        float scl = 1.f / (1.f + rotc[0] * rotc[0] * rotor[b]);
        float coef;
        if (t == 0) coef = scl;
        else if (t == 3) coef = -hydro[0] * hydro[0] * scl;
        else coef = -hbond[0] * hbond[0] * scl;
        atomicAdd(&out[b * 5 + t], v * coef);
    }
    if (t == 4 && tile == 0) {
        float scl = 1.f / (1.f + rotc[0] * rotc[0] * rotor[b]);
        atomicAdd(&out[b * 5 + 4], duff[b] * vdwc[0] * vdwc[0] * scl);
    }
}

extern "C" void kernel_launch(void* const* d_in, const int* in_sizes, int n_in,
                              void* d_out, int out_size, void* d_ws, size_t ws_size,
                              hipStream_t stream) {
    const float* h1    = (const float*)d_in[0];
    const float* adj1  = (const float*)d_in[1];
    const float* h2    = (const float*)d_in[2];
    const float* adj2  = (const float*)d_in[3];
    const float* A_int = (const float*)d_in[4];
    const float* pos1  = (const float*)d_in[5];
    const float* pos2  = (const float*)d_in[6];
    const float* rotor = (const float*)d_in[7];
    const float* vr1   = (const float*)d_in[8];
    const float* vr2   = (const float*)d_in[9];
    const float* duff  = (const float*)d_in[10];
    const float* nm1   = (const float*)d_in[11];
    const float* nm2   = (const float*)d_in[12];
    const float* nodeW = (const float*)d_in[13];
    const float* gatW  = (const float*)d_in[14];
    const float* gatb  = (const float*)d_in[15];
    const float* gatA  = (const float*)d_in[16];
    const float* gateW = (const float*)d_in[17];
    const float* gateb = (const float*)d_in[18];
    const float* vA_W1 = (const float*)d_in[19];
    const float* vA_b1 = (const float*)d_in[20];
    const float* vA_W2 = (const float*)d_in[21];
    const float* vA_b2 = (const float*)d_in[22];
    const float* vB_W1 = (const float*)d_in[23];
    const float* vB_b1 = (const float*)d_in[24];
    const float* vB_W2 = (const float*)d_in[25];
    const float* vB_b2 = (const float*)d_in[26];
    const float* hbond = (const float*)d_in[27];
    const float* hydro = (const float*)d_in[28];
    const float* vdwc  = (const float*)d_in[29];
    const float* rotc  = (const float*)d_in[30];

    float* p = (float*)d_ws;
    float* g     = p; p += (size_t)ROWS * D;
    float* aA    = p; p += (size_t)ROWS * D;
    float* aB    = p; p += (size_t)ROWS * D;
    float* svals = p; p += CSR_ELEMS;
    float2* rowstat = (float2*)p; p += 2 * (size_t)ROWS;
    HT* hbuf  = (HT*)p; p += (size_t)ROWS * D / 2;   // half: ROWS*D*2 bytes
    HT* hAbuf = (HT*)p; p += (size_t)ROWS * D / 2;
    unsigned short* csr = (unsigned short*)p;
    int* nnz = (int*)(csr + CSR_ELEMS);
    float* outp = (float*)d_out;

    k_csrembed<<<ROWS, 128, 0, stream>>>(h1, h2, adj1, adj2, nodeW, g, csr, nnz, outp);

    for (int l = 0; l < 3; ++l) {
        const float* W  = gatW  + (size_t)l * D * D;
        const float* bb = gatb  + (size_t)l * D;
        const float* A  = gatA  + (size_t)l * D * D;
        const float* gW = gateW + (size_t)l * 2 * D;
        const float* gb = gateb + l;
        k_h<<<ROWS / 16, 256, 0, stream>>>(g, W, bb, A, hbuf, hAbuf);
        k_Ssp<<<ROWS, 128, 0, stream>>>(hbuf, hAbuf, csr, nnz, svals, rowstat);
        k_hpgate<<<ROWS, 128, 0, stream>>>(hbuf, g, svals, rowstat, csr, nnz, gW, gb);
    }

    k_pairpre<<<ROWS / 16, 256, 0, stream>>>(g, vA_W1, vB_W1, vA_b1, vB_b1, aA, aB);
    k_pairz<<<512, 256, 0, stream>>>(aA, aB, vA_W2, vB_W2, vA_b2, vB_b2,
                                     pos1, pos2, vr1, vr2, nm1, nm2, A_int,
                                     rotor, duff, hbond, hydro, vdwc, rotc, outp);
}

// Round 10
// 261.491 us; speedup vs baseline: 1.6982x; 1.0914x over previous
//
#include <hip/hip_runtime.h>
#include <hip/hip_fp16.h>
#include <math.h>

#define D 128
#define NB 8
#define NN1 128
#define NN2 512
#define ROWS1 (NB * NN1)          // 1024
#define ROWS2 (NB * NN2)          // 4096
#define ROWS (ROWS1 + ROWS2)      // 5120
#define CAP1 96
#define CAP2 160
#define CSR_ELEMS ((size_t)ROWS1 * CAP1 + (size_t)ROWS2 * CAP2)

typedef __half HT;

__device__ __forceinline__ void resolve_row(int row, int& base_row, size_t& cbase,
                                            int& N) {
    if (row < ROWS1) {
        base_row = row & ~127;
        cbase = (size_t)row * CAP1;
        N = NN1;
    } else {
        int r = row - ROWS1;
        base_row = ROWS1 + (r & ~511);
        cbase = (size_t)ROWS1 * CAP1 + (size_t)r * CAP2;
        N = NN2;
    }
}

// XCD swizzle (validated R8: -23us). 4-row blocks: 1280 blocks, batch=bid&7.
__device__ __forceinline__ int swiz_row4(int bid) {
    int batch = bid & 7, gi = bid >> 3;                 // gi in [0,160)
    return (gi < 32) ? batch * NN1 + gi * 4
                     : ROWS1 + batch * NN2 + (gi - 32) * 4;
}
__device__ __forceinline__ int swiz_row(int bid) {      // 5120 row blocks
    int batch = bid & 7, idx = bid >> 3;
    return (idx < NN1) ? batch * NN1 + idx
                       : ROWS1 + batch * NN2 + (idx - NN1);
}

// load 8 halves (16B) -> 8 floats
__device__ __forceinline__ void load8h(const HT* p, float* o) {
    float4 raw = *(const float4*)p;
    const __half2* h2 = (const __half2*)&raw;
    float2 f0 = __half22float2(h2[0]);
    float2 f1 = __half22float2(h2[1]);
    float2 f2 = __half22float2(h2[2]);
    float2 f3 = __half22float2(h2[3]);
    o[0] = f0.x; o[1] = f0.y; o[2] = f1.x; o[3] = f1.y;
    o[4] = f2.x; o[5] = f2.y; o[6] = f3.x; o[7] = f3.y;
}

// 4-row GEMM from xs (LDS) with weights W: thread (d = t&127, rh = t>>7) owns
// rows rh*2, rh*2+1 at column d. LDS reads are broadcast (address d-invariant).
#define GEMM4(XS, W, BV, STMT0, STMT1)                                        \
    {                                                                         \
        float acc0 = (BV), acc1 = (BV);                                       \
        for (int k0 = 0; k0 < D; k0 += 4) {                                   \
            float w0 = (W)[(k0 + 0) * D + d];                                 \
            float w1 = (W)[(k0 + 1) * D + d];                                 \
            float w2 = (W)[(k0 + 2) * D + d];                                 \
            float w3 = (W)[(k0 + 3) * D + d];                                 \
            float4 x0 = *(const float4*)&XS[rh * 2 + 0][k0];                  \
            float4 x1 = *(const float4*)&XS[rh * 2 + 1][k0];                  \
            acc0 += x0.x * w0 + x0.y * w1 + x0.z * w2 + x0.w * w3;            \
            acc1 += x1.x * w0 + x1.y * w1 + x1.z * w2 + x1.w * w3;            \
        }                                                                     \
        STMT0; STMT1;                                                         \
    }

// ---- k_init: embed + h/hA (layer0) + CSR build + out zero (4 rows/block) ----
__global__ __launch_bounds__(256) void k_init(
    const float* __restrict__ h1in, const float* __restrict__ h2in,
    const float* __restrict__ adj1, const float* __restrict__ adj2,
    const float* __restrict__ nodeW, const float* __restrict__ W,
    const float* __restrict__ bias, const float* __restrict__ A,
    float* __restrict__ g, HT* __restrict__ hOut, HT* __restrict__ hAOut,
    unsigned short* __restrict__ csr, int* __restrict__ nnz,
    float* __restrict__ out) {
    int row0 = swiz_row4(blockIdx.x);
    int t = threadIdx.x;
    if (blockIdx.x == 0 && t < NB * 5) out[t] = 0.f;
    __shared__ float hin[4][54];
    __shared__ float xs[4][D];
    __shared__ float hs[4][D];
    {
        const float* src = (row0 < ROWS1) ? h1in + (size_t)row0 * 54
                                          : h2in + (size_t)(row0 - ROWS1) * 54;
        for (int idx = t; idx < 4 * 54; idx += 256) {
            int r = idx / 54, c = idx - r * 54;
            hin[r][c] = src[(size_t)r * 54 + c];
        }
    }
    __syncthreads();
    int d = t & 127, rh = t >> 7;
    {   // embed: 2 rows / thread
        float e0 = 0.f, e1 = 0.f;
        for (int k = 0; k < 54; ++k) {
            float w = nodeW[k * D + d];
            e0 += hin[rh * 2 + 0][k] * w;
            e1 += hin[rh * 2 + 1][k] * w;
        }
        xs[rh * 2 + 0][d] = e0;
        xs[rh * 2 + 1][d] = e1;
        g[((size_t)row0 + rh * 2 + 0) * D + d] = e0;
        g[((size_t)row0 + rh * 2 + 1) * D + d] = e1;
    }
    __syncthreads();
    float bv = bias[d];
    GEMM4(xs, W, bv,
          { hs[rh * 2 + 0][d] = acc0;
            hOut[((size_t)row0 + rh * 2 + 0) * D + d] = __float2half(acc0); },
          { hs[rh * 2 + 1][d] = acc1;
            hOut[((size_t)row0 + rh * 2 + 1) * D + d] = __float2half(acc1); })
    __syncthreads();
    GEMM4(hs, A, 0.f,
          { hAOut[((size_t)row0 + rh * 2 + 0) * D + d] = __float2half(acc0); },
          { hAOut[((size_t)row0 + rh * 2 + 1) * D + d] = __float2half(acc1); })
    // CSR phase: wave wv handles row row0+wv (independent of LDS above)
    {
        int lane = t & 63, wv = t >> 6;
        int row = row0 + wv;
        int base_row, N;
        size_t cbase;
        resolve_row(row, base_row, cbase, N);
        int cap = (row < ROWS1) ? CAP1 : CAP2;
        const float* arow = (row < ROWS1) ? adj1 + (size_t)row * NN1
                                          : adj2 + (size_t)(row - ROWS1) * NN2;
        int cnt = 0;
        for (int c0 = 0; c0 < N; c0 += 64) {
            float v = arow[c0 + lane];
            unsigned long long m = __ballot(v > 0.f);
            int rank = __popcll(m & ((1ull << lane) - 1ull));
            if (v > 0.f && cnt + rank < cap)
                csr[cbase + cnt + rank] = (unsigned short)(c0 + lane);
            cnt += __popcll(m);
        }
        if (lane == 0) nnz[row] = cnt < cap ? cnt : cap;
    }
}

// ---- sparse S row + softmax stats (unchanged R9: swizzled, fp16) ----
__global__ __launch_bounds__(128) void k_Ssp(const HT* __restrict__ h,
                                             const HT* __restrict__ hA,
                                             const unsigned short* __restrict__ csr,
                                             const int* __restrict__ nnz,
                                             float* __restrict__ svals,
                                             float2* __restrict__ rowstat) {
    int row = swiz_row(blockIdx.x);
    int t = threadIdx.x;
    int base_row, N;
    size_t cbase;
    resolve_row(row, base_row, cbase, N);
    int n = nnz[row];
    int grp = t >> 4, u = t & 15;
    float hi[8], ai[8];
    load8h(h + (size_t)row * D + u * 8, hi);
    load8h(hA + (size_t)row * D + u * 8, ai);
    __shared__ float sv[CAP2];
    for (int s0 = 0; s0 < n; s0 += 16) {
        int sa = s0 + grp;
        int sb = sa + 8;
        float pa = 0.f, pb = 0.f;
        if (sa < n) {
            int jrow = base_row + csr[cbase + sa];
            float hj[8], aj[8];
            load8h(h + (size_t)jrow * D + u * 8, hj);
            load8h(hA + (size_t)jrow * D + u * 8, aj);
#pragma unroll
            for (int q = 0; q < 8; ++q) pa += hi[q] * aj[q] + ai[q] * hj[q];
        }
        if (sb < n) {
            int jrow = base_row + csr[cbase + sb];
            float hj[8], aj[8];
            load8h(h + (size_t)jrow * D + u * 8, hj);
            load8h(hA + (size_t)jrow * D + u * 8, aj);
#pragma unroll
            for (int q = 0; q < 8; ++q) pb += hi[q] * aj[q] + ai[q] * hj[q];
        }
#pragma unroll
        for (int o = 8; o > 0; o >>= 1) {
            pa += __shfl_xor(pa, o);
            pb += __shfl_xor(pb, o);
        }
        if (u == 0) {
            if (sa < n) sv[sa] = pa;
            if (sb < n) sv[sb] = pb;
        }
    }
    __syncthreads();
    if (t < 64) {
        float m = -3.4e38f;
        for (int s = t; s < n; s += 64) m = fmaxf(m, sv[s]);
#pragma unroll
        for (int o = 32; o > 0; o >>= 1) m = fmaxf(m, __shfl_xor(m, o));
        float sum = 0.f;
        for (int s = t; s < n; s += 64) sum += expf(sv[s] - m);
#pragma unroll
        for (int o = 32; o > 0; o >>= 1) sum += __shfl_xor(sum, o);
        if (t == 0) rowstat[row] = make_float2(m, 1.f / sum);
    }
    for (int s = t; s < n; s += 128) svals[cbase + s] = sv[s];
}

// ---- shared gather+gate phase: wave wv handles row row0+wv, writes xs[wv] ----
// Wave-local LDS (av/ax written+read by same wave; no barrier needed - R7 precedent).
__device__ __forceinline__ void gate4(
    int row0, int t, const HT* __restrict__ hIn, float* __restrict__ g,
    const float* __restrict__ svals, const float2* __restrict__ rowstat,
    const unsigned short* __restrict__ csr, const int* __restrict__ nnz,
    const float* __restrict__ gW, float gb0, float (*xs)[D],
    float av[4][CAP2], unsigned short ax[4][CAP2]) {
    int lane = t & 63, wv = t >> 6;
    int row = row0 + wv;
    int base_row, N;
    size_t cbase;
    resolve_row(row, base_row, cbase, N);
    int n = nnz[row];
    for (int s = lane; s < n; s += 64) {
        int jl = csr[cbase + s];
        float2 st = rowstat[base_row + jl];
        av[wv][s] = expf(svals[cbase + s] - st.x) * st.y;
        ax[wv][s] = (unsigned short)jl;
    }
    const __half2* hb2 = (const __half2*)hIn;
    size_t boff = ((size_t)base_row << 6) + lane;   // base_row*64 half2 units
    float2 a[8];
#pragma unroll
    for (int u = 0; u < 8; ++u) a[u] = make_float2(0.f, 0.f);
    int s = 0;
    for (; s + 8 <= n; s += 8) {
#pragma unroll
        for (int u = 0; u < 8; ++u) {
            float avv = av[wv][s + u];
            float2 f = __half22float2(hb2[boff + ((size_t)ax[wv][s + u] << 6)]);
            a[u].x += avv * f.x;
            a[u].y += avv * f.y;
        }
    }
    for (; s < n; ++s) {
        float avv = av[wv][s];
        float2 f = __half22float2(hb2[boff + ((size_t)ax[wv][s] << 6)]);
        a[0].x += avv * f.x;
        a[0].y += avv * f.y;
    }
    float hv0 = fmaxf(((a[0].x + a[1].x) + (a[2].x + a[3].x)) +
                      ((a[4].x + a[5].x) + (a[6].x + a[7].x)), 0.f);
    float hv1 = fmaxf(((a[0].y + a[1].y) + (a[2].y + a[3].y)) +
                      ((a[4].y + a[5].y) + (a[6].y + a[7].y)), 0.f);
    float2 xv = *(const float2*)&g[(size_t)row * D + 2 * lane];
    float2 w01 = *(const float2*)&gW[2 * lane];
    float2 w23 = *(const float2*)&gW[D + 2 * lane];
    float part = xv.x * w01.x + xv.y * w01.y + hv0 * w23.x + hv1 * w23.y;
#pragma unroll
    for (int o = 32; o > 0; o >>= 1) part += __shfl_xor(part, o);
    float c = 1.f / (1.f + expf(-(part + gb0)));
    float g0 = c * xv.x + (1.f - c) * hv0;
    float g1 = c * xv.y + (1.f - c) * hv1;
    xs[wv][2 * lane] = g0;
    xs[wv][2 * lane + 1] = g1;
    *(float2*)&g[(size_t)row * D + 2 * lane] = make_float2(g0, g1);
}

// ---- k_gh: fused gate(layer l) + h/hA GEMMs (layer l+1), 4 rows/block ----
__global__ __launch_bounds__(256) void k_gh(
    const HT* __restrict__ hIn, float* __restrict__ g,
    const float* __restrict__ svals, const float2* __restrict__ rowstat,
    const unsigned short* __restrict__ csr, const int* __restrict__ nnz,
    const float* __restrict__ gW, const float* __restrict__ gb,
    const float* __restrict__ W, const float* __restrict__ bias,
    const float* __restrict__ A, HT* __restrict__ hOut, HT* __restrict__ hAOut) {
    int row0 = swiz_row4(blockIdx.x);
    int t = threadIdx.x;
    __shared__ float xs[4][D];
    __shared__ float hs[4][D];
    __shared__ float av[4][CAP2];
    __shared__ unsigned short ax[4][CAP2];
    gate4(row0, t, hIn, g, svals, rowstat, csr, nnz, gW, gb[0], xs, av, ax);
    __syncthreads();
    int d = t & 127, rh = t >> 7;
    float bv = bias[d];
    GEMM4(xs, W, bv,
          { hs[rh * 2 + 0][d] = acc0;
            hOut[((size_t)row0 + rh * 2 + 0) * D + d] = __float2half(acc0); },
          { hs[rh * 2 + 1][d] = acc1;
            hOut[((size_t)row0 + rh * 2 + 1) * D + d] = __float2half(acc1); })
    __syncthreads();
    GEMM4(hs, A, 0.f,
          { hAOut[((size_t)row0 + rh * 2 + 0) * D + d] = __float2half(acc0); },
          { hAOut[((size_t)row0 + rh * 2 + 1) * D + d] = __float2half(acc1); })
}

// ---- k_gp: fused gate(layer 2) + pair-MLP precompute GEMMs ----
__global__ __launch_bounds__(256) void k_gp(
    const HT* __restrict__ hIn, float* __restrict__ g,
    const float* __restrict__ svals, const float2* __restrict__ rowstat,
    const unsigned short* __restrict__ csr, const int* __restrict__ nnz,
    const float* __restrict__ gW, const float* __restrict__ gb,
    const float* __restrict__ WA, const float* __restrict__ WB,
    const float* __restrict__ bA, const float* __restrict__ bB,
    float* __restrict__ aA, float* __restrict__ aB) {
    int row0 = swiz_row4(blockIdx.x);
    int t = threadIdx.x;
    __shared__ float xs[4][D];
    __shared__ float av[4][CAP2];
    __shared__ unsigned short ax[4][CAP2];
    gate4(row0, t, hIn, g, svals, rowstat, csr, nnz, gW, gb[0], xs, av, ax);
    __syncthreads();
    int d = t & 127, rh = t >> 7;
    int g2 = (row0 >= ROWS1);
    const float* WAp = g2 ? WA + D * D : WA;
    const float* WBp = g2 ? WB + D * D : WB;
    float bvA = g2 ? 0.f : bA[d];
    float bvB = g2 ? 0.f : bB[d];
    GEMM4(xs, WAp, bvA,
          { aA[((size_t)row0 + rh * 2 + 0) * D + d] = acc0; },
          { aA[((size_t)row0 + rh * 2 + 1) * D + d] = acc1; })
    GEMM4(xs, WBp, bvB,
          { aB[((size_t)row0 + rh * 2 + 0) * D + d] = acc0; },
          { aB[((size_t)row0 + rh * 2 + 1) * D + d] = acc1; })
}

// --------- fused pair z-GEMM + energies + atomic output (unchanged R9) -----
__global__ __launch_bounds__(256) void k_pairz(
    const float* __restrict__ aA, const float* __restrict__ aB,
    const float* __restrict__ w2A, const float* __restrict__ w2B,
    const float* __restrict__ b2A, const float* __restrict__ b2B,
    const float* __restrict__ pos1, const float* __restrict__ pos2,
    const float* __restrict__ vr1, const float* __restrict__ vr2,
    const float* __restrict__ nm1, const float* __restrict__ nm2,
    const float* __restrict__ A_int, const float* __restrict__ rotor,
    const float* __restrict__ duff, const float* __restrict__ hbond,
    const float* __restrict__ hydro, const float* __restrict__ vdwc,
    const float* __restrict__ rotc, float* __restrict__ out) {
    int b = blockIdx.x & 7;
    int tile = blockIdx.x >> 3;
    int itile = tile >> 4, jtile = tile & 15;
    int i0 = itile * 32, j0 = jtile * 32;
    int t = threadIdx.x;
    int tx = t & 15, ty = t >> 4;
    __shared__ float A1a[32][20], A1b[32][20], A2a[32][20], A2b[32][20];
    __shared__ float w2As[128], w2Bs[128];
    __shared__ float zAs[32][33], zBs[32][33];
    __shared__ float redc[8][4];
    if (t < 128) { w2As[t] = w2A[t]; w2Bs[t] = w2B[t]; }
    float zA[2][2] = {{0.f, 0.f}, {0.f, 0.f}};
    float zB[2][2] = {{0.f, 0.f}, {0.f, 0.f}};
    int half = t >> 7, idx = t & 127;
    int sr = idx >> 2, sc = (idx & 3) * 4;
    size_t grow = half ? (size_t)(ROWS1 + b * NN2 + j0 + sr)
                       : (size_t)(b * NN1 + i0 + sr);
    for (int hc = 0; hc < D; hc += 16) {
        __syncthreads();
        float4 va = *(const float4*)&aA[grow * D + hc + sc];
        float4 vb = *(const float4*)&aB[grow * D + hc + sc];
        if (half) { *(float4*)&A2a[sr][sc] = va; *(float4*)&A2b[sr][sc] = vb; }
        else      { *(float4*)&A1a[sr][sc] = va; *(float4*)&A1b[sr][sc] = vb; }
        __syncthreads();
#pragma unroll
        for (int hh = 0; hh < 16; hh += 4) {
            float4 wA = *(const float4*)&w2As[hc + hh];
            float4 wB = *(const float4*)&w2Bs[hc + hh];
            float4 xA0 = *(const float4*)&A1a[ty][hh];
            float4 xA1 = *(const float4*)&A1a[ty + 16][hh];
            float4 xB0 = *(const float4*)&A1b[ty][hh];
            float4 xB1 = *(const float4*)&A1b[ty + 16][hh];
            float4 yA0 = *(const float4*)&A2a[tx][hh];
            float4 yA1 = *(const float4*)&A2a[tx + 16][hh];
            float4 yB0 = *(const float4*)&A2b[tx][hh];
            float4 yB1 = *(const float4*)&A2b[tx + 16][hh];
#define RD4(xx, yy, ww) (fmaxf(xx.x + yy.x, 0.f) * ww.x + fmaxf(xx.y + yy.y, 0.f) * ww.y + \
                         fmaxf(xx.z + yy.z, 0.f) * ww.z + fmaxf(xx.w + yy.w, 0.f) * ww.w)
            zA[0][0] += RD4(xA0, yA0, wA); zA[0][1] += RD4(xA0, yA1, wA);
            zA[1][0] += RD4(xA1, yA0, wA); zA[1][1] += RD4(xA1, yA1, wA);
            zB[0][0] += RD4(xB0, yB0, wB); zB[0][1] += RD4(xB0, yB1, wB);
            zB[1][0] += RD4(xB1, yB0, wB); zB[1][1] += RD4(xB1, yB1, wB);
#undef RD4
        }
    }
#pragma unroll
    for (int u = 0; u < 2; ++u)
#pragma unroll
        for (int v = 0; v < 2; ++v) {
            zAs[ty + 16 * u][tx + 16 * v] = zA[u][v];
            zBs[ty + 16 * u][tx + 16 * v] = zB[u][v];
        }
    __syncthreads();
    int j2 = t & 31, ig = t >> 5;
    int jg = j0 + j2;
    size_t j_off = (size_t)b * NN2 + jg;
    float p2x = pos2[j_off * 3 + 0], p2y = pos2[j_off * 3 + 1], p2z = pos2[j_off * 3 + 2];
    float r2 = vr2[j_off], m2 = nm2[j_off];
    float zb2A = b2A[0], zb2B = b2B[0];
    float eV[4], e1[4], e2[4], eH[4];
#pragma unroll
    for (int ii = 0; ii < 4; ++ii) {
        int il = ig * 4 + ii;
        int iglob = i0 + il;
        size_t i_off = (size_t)b * NN1 + iglob;
        float zAv = zAs[il][j2] + zb2A;
        float zBv = zBs[il][j2] + zb2B;
        float dx = pos1[i_off * 3 + 0] - p2x;
        float dy = pos1[i_off * 3 + 1] - p2y;
        float dz = pos1[i_off * 3 + 2] - p2z;
        float dm = sqrtf(dx * dx + dy * dy + dz * dz + 1e-10f);
        if (dm < 0.5f) dm = 1e10f;
        float A_w = 1.f / (1.f + expf(-zAv));
        float B_w = tanhf(zBv) * 0.2f;
        float dm0 = vr1[i_off] + r2 + B_w;
        float dm0s = (dm0 < 1e-4f) ? 1.f : dm0;
        float rr = dm0s / dm;
        float rr2 = rr * rr;
        float rN = rr2 * rr2 * rr2;
        float evdw = fminf(rN * rN - 2.f * rN, 100.f);
        float mask = nm1[i_off] * m2;
        float Aamp = A_w * (0.0356f - 0.0178f) + 0.0178f;
        eV[ii] = Aamp * evdw * mask;
        float dmd = dm - dm0;
        size_t abase = (((size_t)b * 8) * NN1 + iglob) * NN2 + jg;
        float Ai1 = A_int[abase + (size_t)1 * NN1 * NN2];
        float Ai6 = A_int[abase + (size_t)6 * NN1 * NN2];
        float Ai7 = A_int[abase + (size_t)7 * NN1 * NN2];
        e1[ii] = fminf(fmaxf(dmd * Ai1 * (-1.f / 0.7f), 0.f), 1.f);
        e2[ii] = fminf(fmaxf(dmd * Ai7 * (-1.f / 0.7f), 0.f), 1.f);
        eH[ii] = fminf(fmaxf((1.5f - dmd) * Ai6, 0.f), 1.f);
    }
    float sV = (eV[0] + eV[1]) + (eV[2] + eV[3]);
    float s1 = (e1[0] + e1[1]) + (e1[2] + e1[3]);
    float s2 = (e2[0] + e2[1]) + (e2[2] + e2[3]);
    float sH = (eH[0] + eH[1]) + (eH[2] + eH[3]);
#pragma unroll
    for (int o = 16; o > 0; o >>= 1) {
        sV += __shfl_xor(sV, o);
        s1 += __shfl_xor(s1, o);
        s2 += __shfl_xor(s2, o);
        sH += __shfl_xor(sH, o);
    }
    if (j2 == 0) {
        redc[ig][0] = sV; redc[ig][1] = s1; redc[ig][2] = s2; redc[ig][3] = sH;
    }
    __syncthreads();
    if (t < 4) {
        float v = 0.f;
#pragma unroll
        for (int gg = 0; gg < 8; ++gg) v += redc[gg][t];
        float scl = 1.f / (1.f + rotc[0] * rotc[0] * rotor[b]);
        float coef;
        if (t == 0) coef = scl;
        else if (t == 3) coef = -hydro[0] * hydro[0] * scl;
        else coef = -hbond[0] * hbond[0] * scl;
        atomicAdd(&out[b * 5 + t], v * coef);
    }
    if (t == 4 && tile == 0) {
        float scl = 1.f / (1.f + rotc[0] * rotc[0] * rotor[b]);
        atomicAdd(&out[b * 5 + 4], duff[b] * vdwc[0] * vdwc[0] * scl);
    }
}

extern "C" void kernel_launch(void* const* d_in, const int* in_sizes, int n_in,
                              void* d_out, int out_size, void* d_ws, size_t ws_size,
                              hipStream_t stream) {
    const float* h1    = (const float*)d_in[0];
    const float* adj1  = (const float*)d_in[1];
    const float* h2    = (const float*)d_in[2];
    const float* adj2  = (const float*)d_in[3];
    const float* A_int = (const float*)d_in[4];
    const float* pos1  = (const float*)d_in[5];
    const float* pos2  = (const float*)d_in[6];
    const float* rotor = (const float*)d_in[7];
    const float* vr1   = (const float*)d_in[8];
    const float* vr2   = (const float*)d_in[9];
    const float* duff  = (const float*)d_in[10];
    const float* nm1   = (const float*)d_in[11];
    const float* nm2   = (const float*)d_in[12];
    const float* nodeW = (const float*)d_in[13];
    const float* gatW  = (const float*)d_in[14];
    const float* gatb  = (const float*)d_in[15];
    const float* gatA  = (const float*)d_in[16];
    const float* gateW = (const float*)d_in[17];
    const float* gateb = (const float*)d_in[18];
    const float* vA_W1 = (const float*)d_in[19];
    const float* vA_b1 = (const float*)d_in[20];
    const float* vA_W2 = (const float*)d_in[21];
    const float* vA_b2 = (const float*)d_in[22];
    const float* vB_W1 = (const float*)d_in[23];
    const float* vB_b1 = (const float*)d_in[24];
    const float* vB_W2 = (const float*)d_in[25];
    const float* vB_b2 = (const float*)d_in[26];
    const float* hbond = (const float*)d_in[27];
    const float* hydro = (const float*)d_in[28];
    const float* vdwc  = (const float*)d_in[29];
    const float* rotc  = (const float*)d_in[30];

    float* p = (float*)d_ws;
    float* g     = p; p += (size_t)ROWS * D;
    float* aA    = p; p += (size_t)ROWS * D;
    float* aB    = p; p += (size_t)ROWS * D;
    float* svals = p; p += CSR_ELEMS;
    float2* rowstat = (float2*)p; p += 2 * (size_t)ROWS;
    HT* hb0 = (HT*)p; p += (size_t)ROWS * D / 2;
    HT* hA0 = (HT*)p; p += (size_t)ROWS * D / 2;
    HT* hb1 = (HT*)p; p += (size_t)ROWS * D / 2;
    HT* hA1 = (HT*)p; p += (size_t)ROWS * D / 2;
    unsigned short* csr = (unsigned short*)p;
    int* nnz = (int*)(csr + CSR_ELEMS);
    float* outp = (float*)d_out;

    k_init<<<ROWS / 4, 256, 0, stream>>>(h1, h2, adj1, adj2, nodeW, gatW, gatb, gatA,
                                         g, hb0, hA0, csr, nnz, outp);
    // layer 0
    k_Ssp<<<ROWS, 128, 0, stream>>>(hb0, hA0, csr, nnz, svals, rowstat);
    k_gh<<<ROWS / 4, 256, 0, stream>>>(hb0, g, svals, rowstat, csr, nnz,
                                       gateW, gateb,
                                       gatW + (size_t)1 * D * D, gatb + D,
                                       gatA + (size_t)1 * D * D, hb1, hA1);
    // layer 1
    k_Ssp<<<ROWS, 128, 0, stream>>>(hb1, hA1, csr, nnz, svals, rowstat);
    k_gh<<<ROWS / 4, 256, 0, stream>>>(hb1, g, svals, rowstat, csr, nnz,
                                       gateW + 2 * D, gateb + 1,
                                       gatW + (size_t)2 * D * D, gatb + 2 * D,
                                       gatA + (size_t)2 * D * D, hb0, hA0);
    // layer 2
    k_Ssp<<<ROWS, 128, 0, stream>>>(hb0, hA0, csr, nnz, svals, rowstat);
    k_gp<<<ROWS / 4, 256, 0, stream>>>(hb0, g, svals, rowstat, csr, nnz,
                                       gateW + 4 * D, gateb + 2,
                                       vA_W1, vB_W1, vA_b1, vB_b1, aA, aB);

    k_pairz<<<512, 256, 0, stream>>>(aA, aB, vA_W2, vB_W2, vA_b2, vB_b2,
                                     pos1, pos2, vr1, vr2, nm1, nm2, A_int,
                                     rotor, duff, hbond, hydro, vdwc, rotc, outp);
}

// Round 11
// 257.222 us; speedup vs baseline: 1.7264x; 1.0166x over previous
//
#include <hip/hip_runtime.h>
#include <hip/hip_fp16.h>
#include <math.h>

#define D 128
#define NB 8
#define NN1 128
#define NN2 512
#define ROWS1 (NB * NN1)          // 1024
#define ROWS2 (NB * NN2)          // 4096
#define ROWS (ROWS1 + ROWS2)      // 5120
#define CAP1 96
#define CAP2 160
#define CSR_ELEMS ((size_t)ROWS1 * CAP1 + (size_t)ROWS2 * CAP2)

typedef __half HT;

__device__ __forceinline__ void resolve_row(int row, int& base_row, size_t& cbase,
                                            int& N) {
    if (row < ROWS1) {
        base_row = row & ~127;
        cbase = (size_t)row * CAP1;
        N = NN1;
    } else {
        int r = row - ROWS1;
        base_row = ROWS1 + (r & ~511);
        cbase = (size_t)ROWS1 * CAP1 + (size_t)r * CAP2;
        N = NN2;
    }
}

// XCD swizzle (validated R8: -23us). batch = bid & 7.
__device__ __forceinline__ int swiz_row4(int bid) {     // 1280 4-row blocks
    int batch = bid & 7, gi = bid >> 3;                 // gi in [0,160)
    return (gi < 32) ? batch * NN1 + gi * 4
                     : ROWS1 + batch * NN2 + (gi - 32) * 4;
}
__device__ __forceinline__ int swiz_row2(int bid) {     // 2560 2-row blocks
    int batch = bid & 7, gi = bid >> 3;                 // gi in [0,320)
    return (gi < 64) ? batch * NN1 + gi * 2
                     : ROWS1 + batch * NN2 + (gi - 64) * 2;
}

// load 8 halves (16B) -> 8 floats
__device__ __forceinline__ void load8h(const HT* p, float* o) {
    float4 raw = *(const float4*)p;
    const __half2* h2 = (const __half2*)&raw;
    float2 f0 = __half22float2(h2[0]);
    float2 f1 = __half22float2(h2[1]);
    float2 f2 = __half22float2(h2[2]);
    float2 f3 = __half22float2(h2[3]);
    o[0] = f0.x; o[1] = f0.y; o[2] = f1.x; o[3] = f1.y;
    o[4] = f2.x; o[5] = f2.y; o[6] = f3.x; o[7] = f3.y;
}

// 4-row GEMM from xs (LDS): thread (d = t&127, rh = t>>7) owns rows rh*2,
// rh*2+1 at column d. LDS reads broadcast (address d-invariant).
#define GEMM4(XS, W, BV, STMT0, STMT1)                                        \
    {                                                                         \
        float acc0 = (BV), acc1 = (BV);                                       \
        for (int k0 = 0; k0 < D; k0 += 4) {                                   \
            float w0 = (W)[(k0 + 0) * D + d];                                 \
            float w1 = (W)[(k0 + 1) * D + d];                                 \
            float w2 = (W)[(k0 + 2) * D + d];                                 \
            float w3 = (W)[(k0 + 3) * D + d];                                 \
            float4 x0 = *(const float4*)&XS[rh * 2 + 0][k0];                  \
            float4 x1 = *(const float4*)&XS[rh * 2 + 1][k0];                  \
            acc0 += x0.x * w0 + x0.y * w1 + x0.z * w2 + x0.w * w3;            \
            acc1 += x1.x * w0 + x1.y * w1 + x1.z * w2 + x1.w * w3;            \
        }                                                                     \
        STMT0; STMT1;                                                         \
    }

// ---- k_init: embed + h/hA (layer0) + CSR build + out zero (4 rows/block) ----
__global__ __launch_bounds__(256) void k_init(
    const float* __restrict__ h1in, const float* __restrict__ h2in,
    const float* __restrict__ adj1, const float* __restrict__ adj2,
    const float* __restrict__ nodeW, const float* __restrict__ W,
    const float* __restrict__ bias, const float* __restrict__ A,
    float* __restrict__ g, HT* __restrict__ hOut, HT* __restrict__ hAOut,
    unsigned short* __restrict__ csr, int* __restrict__ nnz,
    float* __restrict__ out) {
    int row0 = swiz_row4(blockIdx.x);
    int t = threadIdx.x;
    if (blockIdx.x == 0 && t < NB * 5) out[t] = 0.f;
    __shared__ float hin[4][54];
    __shared__ float xs[4][D];
    __shared__ float hs[4][D];
    {
        const float* src = (row0 < ROWS1) ? h1in + (size_t)row0 * 54
                                          : h2in + (size_t)(row0 - ROWS1) * 54;
        for (int idx = t; idx < 4 * 54; idx += 256) {
            int r = idx / 54, c = idx - r * 54;
            hin[r][c] = src[(size_t)r * 54 + c];
        }
    }
    __syncthreads();
    int d = t & 127, rh = t >> 7;
    {   // embed: 2 rows / thread
        float e0 = 0.f, e1 = 0.f;
        for (int k = 0; k < 54; ++k) {
            float w = nodeW[k * D + d];
            e0 += hin[rh * 2 + 0][k] * w;
            e1 += hin[rh * 2 + 1][k] * w;
        }
        xs[rh * 2 + 0][d] = e0;
        xs[rh * 2 + 1][d] = e1;
        g[((size_t)row0 + rh * 2 + 0) * D + d] = e0;
        g[((size_t)row0 + rh * 2 + 1) * D + d] = e1;
    }
    __syncthreads();
    float bv = bias[d];
    GEMM4(xs, W, bv,
          { hs[rh * 2 + 0][d] = acc0;
            hOut[((size_t)row0 + rh * 2 + 0) * D + d] = __float2half(acc0); },
          { hs[rh * 2 + 1][d] = acc1;
            hOut[((size_t)row0 + rh * 2 + 1) * D + d] = __float2half(acc1); })
    __syncthreads();
    GEMM4(hs, A, 0.f,
          { hAOut[((size_t)row0 + rh * 2 + 0) * D + d] = __float2half(acc0); },
          { hAOut[((size_t)row0 + rh * 2 + 1) * D + d] = __float2half(acc1); })
    // CSR phase: wave wv handles row row0+wv
    {
        int lane = t & 63, wv = t >> 6;
        int row = row0 + wv;
        int base_row, N;
        size_t cbase;
        resolve_row(row, base_row, cbase, N);
        int cap = (row < ROWS1) ? CAP1 : CAP2;
        const float* arow = (row < ROWS1) ? adj1 + (size_t)row * NN1
                                          : adj2 + (size_t)(row - ROWS1) * NN2;
        int cnt = 0;
        for (int c0 = 0; c0 < N; c0 += 64) {
            float v = arow[c0 + lane];
            unsigned long long m = __ballot(v > 0.f);
            int rank = __popcll(m & ((1ull << lane) - 1ull));
            if (v > 0.f && cnt + rank < cap)
                csr[cbase + cnt + rank] = (unsigned short)(c0 + lane);
            cnt += __popcll(m);
        }
        if (lane == 0) nnz[row] = cnt < cap ? cnt : cap;
    }
}

// ---- sparse S + softmax stats: 2 rows / 256-thread block (R11) ----
__global__ __launch_bounds__(256) void k_Ssp(const HT* __restrict__ h,
                                             const HT* __restrict__ hA,
                                             const unsigned short* __restrict__ csr,
                                             const int* __restrict__ nnz,
                                             float* __restrict__ svals,
                                             float2* __restrict__ rowstat) {
    int t = threadIdx.x;
    int half = t >> 7, t2 = t & 127;
    int row = swiz_row2(blockIdx.x) + half;
    int base_row, N;
    size_t cbase;
    resolve_row(row, base_row, cbase, N);
    int n = nnz[row];
    int grp = t2 >> 4, u = t2 & 15;
    float hi[8], ai[8];
    load8h(h + (size_t)row * D + u * 8, hi);
    load8h(hA + (size_t)row * D + u * 8, ai);
    __shared__ float sv[2][CAP2];
    for (int s0 = 0; s0 < n; s0 += 16) {
        int sa = s0 + grp;
        int sb = sa + 8;
        float pa = 0.f, pb = 0.f;
        if (sa < n) {
            int jrow = base_row + csr[cbase + sa];
            float hj[8], aj[8];
            load8h(h + (size_t)jrow * D + u * 8, hj);
            load8h(hA + (size_t)jrow * D + u * 8, aj);
#pragma unroll
            for (int q = 0; q < 8; ++q) pa += hi[q] * aj[q] + ai[q] * hj[q];
        }
        if (sb < n) {
            int jrow = base_row + csr[cbase + sb];
            float hj[8], aj[8];
            load8h(h + (size_t)jrow * D + u * 8, hj);
            load8h(hA + (size_t)jrow * D + u * 8, aj);
#pragma unroll
            for (int q = 0; q < 8; ++q) pb += hi[q] * aj[q] + ai[q] * hj[q];
        }
#pragma unroll
        for (int o = 8; o > 0; o >>= 1) {
            pa += __shfl_xor(pa, o);
            pb += __shfl_xor(pb, o);
        }
        if (u == 0) {
            if (sa < n) sv[half][sa] = pa;
            if (sb < n) sv[half][sb] = pb;
        }
    }
    __syncthreads();
    if (t2 < 64) {   // one full wave per half (t in [0,64) or [128,192))
        float m = -3.4e38f;
        for (int s = t2; s < n; s += 64) m = fmaxf(m, sv[half][s]);
#pragma unroll
        for (int o = 32; o > 0; o >>= 1) m = fmaxf(m, __shfl_xor(m, o));
        float sum = 0.f;
        for (int s = t2; s < n; s += 64) sum += expf(sv[half][s] - m);
#pragma unroll
        for (int o = 32; o > 0; o >>= 1) sum += __shfl_xor(sum, o);
        if (t2 == 0) rowstat[row] = make_float2(m, 1.f / sum);
    }
    for (int s = t2; s < n; s += 128) svals[cbase + s] = sv[half][s];
}

// ---- gather+gate phase: wave wv = row row0+wv; wave-local LDS ----
__device__ __forceinline__ void gate4(
    int row0, int t, const HT* __restrict__ hIn, float* __restrict__ g,
    const float* __restrict__ svals, const float2* __restrict__ rowstat,
    const unsigned short* __restrict__ csr, const int* __restrict__ nnz,
    const float* __restrict__ gW, float gb0, float (*xs)[D],
    float av[4][CAP2], unsigned short ax[4][CAP2], int writeG) {
    int lane = t & 63, wv = t >> 6;
    int row = row0 + wv;
    int base_row, N;
    size_t cbase;
    resolve_row(row, base_row, cbase, N);
    int n = nnz[row];
    for (int s = lane; s < n; s += 64) {
        int jl = csr[cbase + s];
        float2 st = rowstat[base_row + jl];
        av[wv][s] = expf(svals[cbase + s] - st.x) * st.y;
        ax[wv][s] = (unsigned short)jl;
    }
    const __half2* hb2 = (const __half2*)hIn;
    size_t boff = ((size_t)base_row << 6) + lane;
    float2 a[8];
#pragma unroll
    for (int u = 0; u < 8; ++u) a[u] = make_float2(0.f, 0.f);
    int s = 0;
    for (; s + 8 <= n; s += 8) {
#pragma unroll
        for (int u = 0; u < 8; ++u) {
            float avv = av[wv][s + u];
            float2 f = __half22float2(hb2[boff + ((size_t)ax[wv][s + u] << 6)]);
            a[u].x += avv * f.x;
            a[u].y += avv * f.y;
        }
    }
    for (; s < n; ++s) {
        float avv = av[wv][s];
        float2 f = __half22float2(hb2[boff + ((size_t)ax[wv][s] << 6)]);
        a[0].x += avv * f.x;
        a[0].y += avv * f.y;
    }
    float hv0 = fmaxf(((a[0].x + a[1].x) + (a[2].x + a[3].x)) +
                      ((a[4].x + a[5].x) + (a[6].x + a[7].x)), 0.f);
    float hv1 = fmaxf(((a[0].y + a[1].y) + (a[2].y + a[3].y)) +
                      ((a[4].y + a[5].y) + (a[6].y + a[7].y)), 0.f);
    float2 xv = *(const float2*)&g[(size_t)row * D + 2 * lane];
    float2 w01 = *(const float2*)&gW[2 * lane];
    float2 w23 = *(const float2*)&gW[D + 2 * lane];
    float part = xv.x * w01.x + xv.y * w01.y + hv0 * w23.x + hv1 * w23.y;
#pragma unroll
    for (int o = 32; o > 0; o >>= 1) part += __shfl_xor(part, o);
    float c = 1.f / (1.f + expf(-(part + gb0)));
    float g0 = c * xv.x + (1.f - c) * hv0;
    float g1 = c * xv.y + (1.f - c) * hv1;
    xs[wv][2 * lane] = g0;
    xs[wv][2 * lane + 1] = g1;
    if (writeG) *(float2*)&g[(size_t)row * D + 2 * lane] = make_float2(g0, g1);
}

// ---- k_gh: fused gate(layer l) + h/hA GEMMs (layer l+1), 4 rows/block ----
__global__ __launch_bounds__(256) void k_gh(
    const HT* __restrict__ hIn, float* __restrict__ g,
    const float* __restrict__ svals, const float2* __restrict__ rowstat,
    const unsigned short* __restrict__ csr, const int* __restrict__ nnz,
    const float* __restrict__ gW, const float* __restrict__ gb,
    const float* __restrict__ W, const float* __restrict__ bias,
    const float* __restrict__ A, HT* __restrict__ hOut, HT* __restrict__ hAOut) {
    int row0 = swiz_row4(blockIdx.x);
    int t = threadIdx.x;
    __shared__ float xs[4][D];
    __shared__ float hs[4][D];
    __shared__ float av[4][CAP2];
    __shared__ unsigned short ax[4][CAP2];
    gate4(row0, t, hIn, g, svals, rowstat, csr, nnz, gW, gb[0], xs, av, ax, 1);
    __syncthreads();
    int d = t & 127, rh = t >> 7;
    float bv = bias[d];
    GEMM4(xs, W, bv,
          { hs[rh * 2 + 0][d] = acc0;
            hOut[((size_t)row0 + rh * 2 + 0) * D + d] = __float2half(acc0); },
          { hs[rh * 2 + 1][d] = acc1;
            hOut[((size_t)row0 + rh * 2 + 1) * D + d] = __float2half(acc1); })
    __syncthreads();
    GEMM4(hs, A, 0.f,
          { hAOut[((size_t)row0 + rh * 2 + 0) * D + d] = __float2half(acc0); },
          { hAOut[((size_t)row0 + rh * 2 + 1) * D + d] = __float2half(acc1); })
}

// ---- k_gp: fused gate(layer 2, no g write-back) + pair-MLP precompute ----
__global__ __launch_bounds__(256) void k_gp(
    const HT* __restrict__ hIn, float* __restrict__ g,
    const float* __restrict__ svals, const float2* __restrict__ rowstat,
    const unsigned short* __restrict__ csr, const int* __restrict__ nnz,
    const float* __restrict__ gW, const float* __restrict__ gb,
    const float* __restrict__ WA, const float* __restrict__ WB,
    const float* __restrict__ bA, const float* __restrict__ bB,
    float* __restrict__ aA, float* __restrict__ aB) {
    int row0 = swiz_row4(blockIdx.x);
    int t = threadIdx.x;
    __shared__ float xs[4][D];
    __shared__ float av[4][CAP2];
    __shared__ unsigned short ax[4][CAP2];
    gate4(row0, t, hIn, g, svals, rowstat, csr, nnz, gW, gb[0], xs, av, ax, 0);
    __syncthreads();
    int d = t & 127, rh = t >> 7;
    int g2 = (row0 >= ROWS1);
    const float* WAp = g2 ? WA + D * D : WA;
    const float* WBp = g2 ? WB + D * D : WB;
    float bvA = g2 ? 0.f : bA[d];
    float bvB = g2 ? 0.f : bB[d];
    GEMM4(xs, WAp, bvA,
          { aA[((size_t)row0 + rh * 2 + 0) * D + d] = acc0; },
          { aA[((size_t)row0 + rh * 2 + 1) * D + d] = acc1; })
    GEMM4(xs, WBp, bvB,
          { aB[((size_t)row0 + rh * 2 + 0) * D + d] = acc0; },
          { aB[((size_t)row0 + rh * 2 + 1) * D + d] = acc1; })
}

// --------- fused pair z-GEMM + energies + atomic output ------------
__global__ __launch_bounds__(256) void k_pairz(
    const float* __restrict__ aA, const float* __restrict__ aB,
    const float* __restrict__ w2A, const float* __restrict__ w2B,
    const float* __restrict__ b2A, const float* __restrict__ b2B,
    const float* __restrict__ pos1, const float* __restrict__ pos2,
    const float* __restrict__ vr1, const float* __restrict__ vr2,
    const float* __restrict__ nm1, const float* __restrict__ nm2,
    const float* __restrict__ A_int, const float* __restrict__ rotor,
    const float* __restrict__ duff, const float* __restrict__ hbond,
    const float* __restrict__ hydro, const float* __restrict__ vdwc,
    const float* __restrict__ rotc, float* __restrict__ out) {
    int b = blockIdx.x & 7;
    int tile = blockIdx.x >> 3;
    int itile = tile >> 4, jtile = tile & 15;
    int i0 = itile * 32, j0 = jtile * 32;
    int t = threadIdx.x;
    int tx = t & 15, ty = t >> 4;
    __shared__ float A1a[32][20], A1b[32][20], A2a[32][20], A2b[32][20];
    __shared__ float w2As[128], w2Bs[128];
    __shared__ float zAs[32][33], zBs[32][33];
    __shared__ float redc[8][4];
    if (t < 128) { w2As[t] = w2A[t]; w2Bs[t] = w2B[t]; }
    float zA[2][2] = {{0.f, 0.f}, {0.f, 0.f}};
    float zB[2][2] = {{0.f, 0.f}, {0.f, 0.f}};
    int half = t >> 7, idx = t & 127;
    int sr = idx >> 2, sc = (idx & 3) * 4;
    size_t grow = half ? (size_t)(ROWS1 + b * NN2 + j0 + sr)
                       : (size_t)(b * NN1 + i0 + sr);
    for (int hc = 0; hc < D; hc += 16) {
        __syncthreads();
        float4 va = *(const float4*)&aA[grow * D + hc + sc];
        float4 vb = *(const float4*)&aB[grow * D + hc + sc];
        if (half) { *(float4*)&A2a[sr][sc] = va; *(float4*)&A2b[sr][sc] = vb; }
        else      { *(float4*)&A1a[sr][sc] = va; *(float4*)&A1b[sr][sc] = vb; }
        __syncthreads();
#pragma unroll
        for (int hh = 0; hh < 16; hh += 4) {
            float4 wA = *(const float4*)&w2As[hc + hh];
            float4 wB = *(const float4*)&w2Bs[hc + hh];
            float4 xA0 = *(const float4*)&A1a[ty][hh];
            float4 xA1 = *(const float4*)&A1a[ty + 16][hh];
            float4 xB0 = *(const float4*)&A1b[ty][hh];
            float4 xB1 = *(const float4*)&A1b[ty + 16][hh];
            float4 yA0 = *(const float4*)&A2a[tx][hh];
            float4 yA1 = *(const float4*)&A2a[tx + 16][hh];
            float4 yB0 = *(const float4*)&A2b[tx][hh];
            float4 yB1 = *(const float4*)&A2b[tx + 16][hh];
#define RD4(xx, yy, ww) (fmaxf(xx.x + yy.x, 0.f) * ww.x + fmaxf(xx.y + yy.y, 0.f) * ww.y + \
                         fmaxf(xx.z + yy.z, 0.f) * ww.z + fmaxf(xx.w + yy.w, 0.f) * ww.w)
            zA[0][0] += RD4(xA0, yA0, wA); zA[0][1] += RD4(xA0, yA1, wA);
            zA[1][0] += RD4(xA1, yA0, wA); zA[1][1] += RD4(xA1, yA1, wA);
            zB[0][0] += RD4(xB0, yB0, wB); zB[0][1] += RD4(xB0, yB1, wB);
            zB[1][0] += RD4(xB1, yB0, wB); zB[1][1] += RD4(xB1, yB1, wB);
#undef RD4
        }
    }
    // --- prefetch all i-side energy inputs BEFORE the zAs LDS round-trip ---
    int j2 = t & 31, ig = t >> 5;
    int jg = j0 + j2;
    size_t j_off = (size_t)b * NN2 + jg;
    float p2x = pos2[j_off * 3 + 0], p2y = pos2[j_off * 3 + 1], p2z = pos2[j_off * 3 + 2];
    float r2 = vr2[j_off], m2 = nm2[j_off];
    float zb2A = b2A[0], zb2B = b2B[0];
    float Ai1r[4], Ai6r[4], Ai7r[4], p1xr[4], p1yr[4], p1zr[4], vr1r[4], nm1r[4];
#pragma unroll
    for (int ii = 0; ii < 4; ++ii) {
        int iglob = i0 + ig * 4 + ii;
        size_t i_off = (size_t)b * NN1 + iglob;
        p1xr[ii] = pos1[i_off * 3 + 0];
        p1yr[ii] = pos1[i_off * 3 + 1];
        p1zr[ii] = pos1[i_off * 3 + 2];
        vr1r[ii] = vr1[i_off];
        nm1r[ii] = nm1[i_off];
        size_t abase = (((size_t)b * 8) * NN1 + iglob) * NN2 + jg;
        Ai1r[ii] = A_int[abase + (size_t)1 * NN1 * NN2];
        Ai6r[ii] = A_int[abase + (size_t)6 * NN1 * NN2];
        Ai7r[ii] = A_int[abase + (size_t)7 * NN1 * NN2];
    }
#pragma unroll
    for (int u = 0; u < 2; ++u)
#pragma unroll
        for (int v = 0; v < 2; ++v) {
            zAs[ty + 16 * u][tx + 16 * v] = zA[u][v];
            zBs[ty + 16 * u][tx + 16 * v] = zB[u][v];
        }
    __syncthreads();
    float eV[4], e1[4], e2[4], eH[4];
#pragma unroll
    for (int ii = 0; ii < 4; ++ii) {
        int il = ig * 4 + ii;
        float zAv = zAs[il][j2] + zb2A;
        float zBv = zBs[il][j2] + zb2B;
        float dx = p1xr[ii] - p2x;
        float dy = p1yr[ii] - p2y;
        float dz = p1zr[ii] - p2z;
        float dm = sqrtf(dx * dx + dy * dy + dz * dz + 1e-10f);
        if (dm < 0.5f) dm = 1e10f;
        float A_w = 1.f / (1.f + expf(-zAv));
        float B_w = tanhf(zBv) * 0.2f;
        float dm0 = vr1r[ii] + r2 + B_w;
        float dm0s = (dm0 < 1e-4f) ? 1.f : dm0;
        float rr = dm0s / dm;
        float rr2 = rr * rr;
        float rN = rr2 * rr2 * rr2;
        float evdw = fminf(rN * rN - 2.f * rN, 100.f);
        float mask = nm1r[ii] * m2;
        float Aamp = A_w * (0.0356f - 0.0178f) + 0.0178f;
        eV[ii] = Aamp * evdw * mask;
        float dmd = dm - dm0;
        e1[ii] = fminf(fmaxf(dmd * Ai1r[ii] * (-1.f / 0.7f), 0.f), 1.f);
        e2[ii] = fminf(fmaxf(dmd * Ai7r[ii] * (-1.f / 0.7f), 0.f), 1.f);
        eH[ii] = fminf(fmaxf((1.5f - dmd) * Ai6r[ii], 0.f), 1.f);
    }
    float sV = (eV[0] + eV[1]) + (eV[2] + eV[3]);
    float s1 = (e1[0] + e1[1]) + (e1[2] + e1[3]);
    float s2 = (e2[0] + e2[1]) + (e2[2] + e2[3]);
    float sH = (eH[0] + eH[1]) + (eH[2] + eH[3]);
#pragma unroll
    for (int o = 16; o > 0; o >>= 1) {
        sV += __shfl_xor(sV, o);
        s1 += __shfl_xor(s1, o);
        s2 += __shfl_xor(s2, o);
        sH += __shfl_xor(sH, o);
    }
    if (j2 == 0) {
        redc[ig][0] = sV; redc[ig][1] = s1; redc[ig][2] = s2; redc[ig][3] = sH;
    }
    __syncthreads();
    if (t < 4) {
        float v = 0.f;
#pragma unroll
        for (int gg = 0; gg < 8; ++gg) v += redc[gg][t];
        float scl = 1.f / (1.f + rotc[0] * rotc[0] * rotor[b]);
        float coef;
        if (t == 0) coef = scl;
        else if (t == 3) coef = -hydro[0] * hydro[0] * scl;
        else coef = -hbond[0] * hbond[0] * scl;
        atomicAdd(&out[b * 5 + t], v * coef);
    }
    if (t == 4 && tile == 0) {
        float scl = 1.f / (1.f + rotc[0] * rotc[0] * rotor[b]);
        atomicAdd(&out[b * 5 + 4], duff[b] * vdwc[0] * vdwc[0] * scl);
    }
}

extern "C" void kernel_launch(void* const* d_in, const int* in_sizes, int n_in,
                              void* d_out, int out_size, void* d_ws, size_t ws_size,
                              hipStream_t stream) {
    const float* h1    = (const float*)d_in[0];
    const float* adj1  = (const float*)d_in[1];
    const float* h2    = (const float*)d_in[2];
    const float* adj2  = (const float*)d_in[3];
    const float* A_int = (const float*)d_in[4];
    const float* pos1  = (const float*)d_in[5];
    const float* pos2  = (const float*)d_in[6];
    const float* rotor = (const float*)d_in[7];
    const float* vr1   = (const float*)d_in[8];
    const float* vr2   = (const float*)d_in[9];
    const float* duff  = (const float*)d_in[10];
    const float* nm1   = (const float*)d_in[11];
    const float* nm2   = (const float*)d_in[12];
    const float* nodeW = (const float*)d_in[13];
    const float* gatW  = (const float*)d_in[14];
    const float* gatb  = (const float*)d_in[15];
    const float* gatA  = (const float*)d_in[16];
    const float* gateW = (const float*)d_in[17];
    const float* gateb = (const float*)d_in[18];
    const float* vA_W1 = (const float*)d_in[19];
    const float* vA_b1 = (const float*)d_in[20];
    const float* vA_W2 = (const float*)d_in[21];
    const float* vA_b2 = (const float*)d_in[22];
    const float* vB_W1 = (const float*)d_in[23];
    const float* vB_b1 = (const float*)d_in[24];
    const float* vB_W2 = (const float*)d_in[25];
    const float* vB_b2 = (const float*)d_in[26];
    const float* hbond = (const float*)d_in[27];
    const float* hydro = (const float*)d_in[28];
    const float* vdwc  = (const float*)d_in[29];
    const float* rotc  = (const float*)d_in[30];

    float* p = (float*)d_ws;
    float* g     = p; p += (size_t)ROWS * D;
    float* aA    = p; p += (size_t)ROWS * D;
    float* aB    = p; p += (size_t)ROWS * D;
    float* svals = p; p += CSR_ELEMS;
    float2* rowstat = (float2*)p; p += 2 * (size_t)ROWS;
    HT* hb0 = (HT*)p; p += (size_t)ROWS * D / 2;
    HT* hA0 = (HT*)p; p += (size_t)ROWS * D / 2;
    HT* hb1 = (HT*)p; p += (size_t)ROWS * D / 2;
    HT* hA1 = (HT*)p; p += (size_t)ROWS * D / 2;
    unsigned short* csr = (unsigned short*)p;
    int* nnz = (int*)(csr + CSR_ELEMS);
    float* outp = (float*)d_out;

    k_init<<<ROWS / 4, 256, 0, stream>>>(h1, h2, adj1, adj2, nodeW, gatW, gatb, gatA,
                                         g, hb0, hA0, csr, nnz, outp);
    // layer 0
    k_Ssp<<<ROWS / 2, 256, 0, stream>>>(hb0, hA0, csr, nnz, svals, rowstat);
    k_gh<<<ROWS / 4, 256, 0, stream>>>(hb0, g, svals, rowstat, csr, nnz,
                                       gateW, gateb,
                                       gatW + (size_t)1 * D * D, gatb + D,
                                       gatA + (size_t)1 * D * D, hb1, hA1);
    // layer 1
    k_Ssp<<<ROWS / 2, 256, 0, stream>>>(hb1, hA1, csr, nnz, svals, rowstat);
    k_gh<<<ROWS / 4, 256, 0, stream>>>(hb1, g, svals, rowstat, csr, nnz,
                                       gateW + 2 * D, gateb + 1,
                                       gatW + (size_t)2 * D * D, gatb + 2 * D,
                                       gatA + (size_t)2 * D * D, hb0, hA0);
    // layer 2
    k_Ssp<<<ROWS / 2, 256, 0, stream>>>(hb0, hA0, csr, nnz, svals, rowstat);
    k_gp<<<ROWS / 4, 256, 0, stream>>>(hb0, g, svals, rowstat, csr, nnz,
                                       gateW + 4 * D, gateb + 2,
                                       vA_W1, vB_W1, vA_b1, vB_b1, aA, aB);

    k_pairz<<<512, 256, 0, stream>>>(aA, aB, vA_W2, vB_W2, vA_b2, vB_b2,
                                     pos1, pos2, vr1, vr2, nm1, nm2, A_int,
                                     rotor, duff, hbond, hydro, vdwc, rotc, outp);
}